// Round 2
// baseline (1406.398 us; speedup 1.0000x reference)
//
#include <hip/hip_runtime.h>

// GaussianMixture energy on MI355X — fp32 baseline, multi-kernel pipeline.
// S=65536 samples, D=128 dims, K=8 components.
//
// Pipeline:
//  1. k_gamma : gamma = softmax(x@W + b)            [S,K] -> ws
//  2. k_m2    : partial M2_k = X^T diag(g_k) X, partial musum, partial Nk
//  3. k_redmu : Nk, mu
//  4. k_sigma : sigma_k = M2_k/Nk - mu mu^T
//  5. k_chol  : Cholesky sigma=LL^T, T=L^{-1}, w=T mu, coef_k=log(phi)-0.5*logdet(2*pi*sigma)
//  6. k_maha  : maha_jk = ||T_k x_j - w_k||^2 ; per-sample log-sum-exp log-density
//  7. k_final : energy = -sum
//
// Round-1 fix: per-sample density computed via online log-sum-exp over the 8
// components (identical in exact arithmetic, no fp32 underflow -> finite energy;
// the fp32 reference underflows to dens=0 -> log(0) -> energy=+inf).

#define S_LEN 65536
#define D 128
#define K 8
#define NCHUNK 64                  // S-chunks in pass 2
#define CHUNK (S_LEN / NCHUNK)     // 1024 samples per m2 block
#define MBLK 64                    // samples per maha block
#define NMB (S_LEN / MBLK)         // 1024 blocks

// workspace layout (float offsets)
#define OFF_GAMMA 0
#define SZ_GAMMA (S_LEN * K)                       // 524288
#define OFF_M2P (OFF_GAMMA + SZ_GAMMA)
#define SZ_M2P (K * NCHUNK * D * D)                // 8388608
#define OFF_MSP (OFF_M2P + SZ_M2P)
#define SZ_MSP (K * NCHUNK * D)                    // 65536
#define OFF_NKP (OFF_MSP + SZ_MSP)
#define SZ_NKP (K * NCHUNK)                        // 512
#define OFF_NK (OFF_NKP + SZ_NKP)
#define OFF_MU (OFF_NK + K)
#define OFF_SIGMA (OFF_MU + K * D)
#define OFF_TT (OFF_SIGMA + K * D * D)
#define OFF_WV (OFF_TT + K * D * D)
#define OFF_COEF (OFF_WV + K * D)
#define OFF_EPART (OFF_COEF + K)
// total floats = OFF_EPART + NMB = 9244176  (~37 MB of d_ws)

#define LOG_2PI 1.8378770664093453f

// ---------------------------------------------------------------- pass 1
__global__ __launch_bounds__(256) void k_gamma(const float* __restrict__ x,
                                               const float* __restrict__ W,
                                               const float* __restrict__ b,
                                               float* __restrict__ gamma) {
  __shared__ float Wt[K][D];   // W transposed: Wt[k][d]
  __shared__ float bl[K];
  int tid = threadIdx.x;
  for (int it = 0; it < 4; ++it) {
    int idx = it * 256 + tid;           // 1024 = D*K
    Wt[idx & 7][idx >> 3] = W[idx];     // W is [D][K] row-major
  }
  if (tid < K) bl[tid] = b[tid];
  __syncthreads();

  int s = blockIdx.x * 256 + tid;
  float li[K];
#pragma unroll
  for (int k = 0; k < K; ++k) li[k] = bl[k];
  const float4* xr = (const float4*)(x + (size_t)s * D);
#pragma unroll 8
  for (int i = 0; i < 32; ++i) {
    float4 xv = xr[i];
#pragma unroll
    for (int k = 0; k < K; ++k) {
      float4 wv = *(const float4*)&Wt[k][i * 4];
      li[k] += xv.x * wv.x + xv.y * wv.y + xv.z * wv.z + xv.w * wv.w;
    }
  }
  float m = li[0];
#pragma unroll
  for (int k = 1; k < K; ++k) m = fmaxf(m, li[k]);
  float p[K];
  float sum = 0.f;
#pragma unroll
  for (int k = 0; k < K; ++k) { p[k] = expf(li[k] - m); sum += p[k]; }
  float inv = 1.0f / sum;
  float4 o0 = {p[0] * inv, p[1] * inv, p[2] * inv, p[3] * inv};
  float4 o1 = {p[4] * inv, p[5] * inv, p[6] * inv, p[7] * inv};
  *(float4*)(gamma + (size_t)s * K) = o0;
  *(float4*)(gamma + (size_t)s * K + 4) = o1;
}

// ---------------------------------------------------------------- pass 2
// per-block: one (k, chunk): M2 tile 128x128 in registers (8x8 per thread)
__global__ __launch_bounds__(256, 2) void k_m2(const float* __restrict__ x,
                                               const float* __restrict__ gamma,
                                               float* __restrict__ m2p,
                                               float* __restrict__ msp,
                                               float* __restrict__ nkp) {
  __shared__ float xs[16][D];
  __shared__ float wx[16][D];
  __shared__ float red16[16];
  int tid = threadIdx.x;
  int c = blockIdx.x, k = blockIdx.y;
  int s0b = c * CHUNK;

  // wave-remapped 16x16 thread-tile grid: within a wave, 8 distinct d-groups
  // x 8 distinct e-groups -> both LDS reads are <=2-way bank aliasing (free).
  int w = tid >> 6, l = tid & 63;
  int d0 = (((w >> 1) << 3) + (l >> 3)) * 8;
  int e0 = (((w & 1) << 3) + (l & 7)) * 8;

  float acc[8][8] = {};
  float msacc = 0.f, gacc = 0.f;
  int js = tid >> 4, ds = (tid & 15) * 8;

  for (int t = 0; t < CHUNK / 16; ++t) {
    int s0 = s0b + t * 16;
    float4 v0 = *(const float4*)(x + (size_t)(s0 + js) * D + ds);
    float4 v1 = *(const float4*)(x + (size_t)(s0 + js) * D + ds + 4);
    float g = gamma[(size_t)(s0 + js) * K + k];
    __syncthreads();   // previous tile's compute done
    *(float4*)&xs[js][ds] = v0;
    *(float4*)&xs[js][ds + 4] = v1;
    float4 w0 = {g * v0.x, g * v0.y, g * v0.z, g * v0.w};
    float4 w1 = {g * v1.x, g * v1.y, g * v1.z, g * v1.w};
    *(float4*)&wx[js][ds] = w0;
    *(float4*)&wx[js][ds + 4] = w1;
    if ((tid & 15) == 0) gacc += g;
    __syncthreads();   // tile staged
#pragma unroll 4
    for (int j = 0; j < 16; ++j) {
      float4 a0 = *(const float4*)&wx[j][d0];
      float4 a1 = *(const float4*)&wx[j][d0 + 4];
      float4 b0 = *(const float4*)&xs[j][e0];
      float4 b1 = *(const float4*)&xs[j][e0 + 4];
      float av[8] = {a0.x, a0.y, a0.z, a0.w, a1.x, a1.y, a1.z, a1.w};
      float bv[8] = {b0.x, b0.y, b0.z, b0.w, b1.x, b1.y, b1.z, b1.w};
#pragma unroll
      for (int di = 0; di < 8; ++di)
#pragma unroll
        for (int ei = 0; ei < 8; ++ei) acc[di][ei] += av[di] * bv[ei];
    }
    if (tid < D) {
#pragma unroll
      for (int j = 0; j < 16; ++j) msacc += wx[j][tid];
    }
  }

  size_t base = (size_t)(k * NCHUNK + c) * (D * D);
#pragma unroll
  for (int di = 0; di < 8; ++di) {
#pragma unroll
    for (int e4 = 0; e4 < 2; ++e4) {
      float4 o = {acc[di][e4 * 4 + 0], acc[di][e4 * 4 + 1],
                  acc[di][e4 * 4 + 2], acc[di][e4 * 4 + 3]};
      *(float4*)(m2p + base + (size_t)(d0 + di) * D + e0 + e4 * 4) = o;
    }
  }
  if (tid < D) msp[(size_t)(k * NCHUNK + c) * D + tid] = msacc;
  if ((tid & 15) == 0) red16[tid >> 4] = gacc;
  __syncthreads();
  if (tid == 0) {
    float s = 0.f;
    for (int i = 0; i < 16; ++i) s += red16[i];
    nkp[k * NCHUNK + c] = s;
  }
}

// ---------------------------------------------------------------- pass 3a
__global__ __launch_bounds__(256) void k_redmu(const float* __restrict__ msp,
                                               const float* __restrict__ nkp,
                                               float* __restrict__ Nk,
                                               float* __restrict__ mu) {
  __shared__ float sNk[K];
  int tid = threadIdx.x;
  if (tid < K) {
    float s = 0.f;
    for (int c = 0; c < NCHUNK; ++c) s += nkp[tid * NCHUNK + c];
    sNk[tid] = s;
    Nk[tid] = s;
  }
  __syncthreads();
  for (int it = 0; it < (K * D) / 256; ++it) {
    int idx = it * 256 + tid;
    int k = idx >> 7;
    float s = 0.f;
    for (int c = 0; c < NCHUNK; ++c) s += msp[(size_t)(k * NCHUNK + c) * D + (idx & 127)];
    mu[idx] = s / sNk[k];
  }
}

// ---------------------------------------------------------------- pass 3b
__global__ __launch_bounds__(256) void k_sigma(const float* __restrict__ m2p,
                                               const float* __restrict__ Nk,
                                               const float* __restrict__ mu,
                                               float* __restrict__ sigma) {
  int tid = threadIdx.x;
  int k = blockIdx.y;
  int flat = blockIdx.x * 256 + tid;
  int d = flat >> 7, e = flat & 127;
  float s = 0.f;
  for (int c = 0; c < NCHUNK; ++c) s += m2p[((size_t)(k * NCHUNK + c) << 14) + flat];
  sigma[((size_t)k << 14) + flat] = s / Nk[k] - mu[k * D + d] * mu[k * D + e];
}

// ---------------------------------------------------------------- pass 4
// One block per component. A kept in exactly-64KB LDS with per-row rotate
// swizzle (c+r)&127 -> every access pattern used here is <=2-way aliased.
// After Cholesky, T = L^{-1} is stored in A's strict upper triangle
// (T[i][c] at A(c,i), c<i); T's diagonal is recomputed as 1/L_ii.
__global__ __launch_bounds__(256) void k_chol(const float* __restrict__ sigma,
                                              const float* __restrict__ Nk,
                                              const float* __restrict__ mu,
                                              float* __restrict__ Tt,
                                              float* __restrict__ wv,
                                              float* __restrict__ coef) {
  __shared__ float sA[D * D];  // 65536 bytes exactly
#define AIDX(r, c) (((r) << 7) + (((c) + (r)) & 127))
  int tid = threadIdx.x;
  int k = blockIdx.x;
  const float* sg = sigma + ((size_t)k << 14);
  for (int it = 0; it < 64; ++it) {
    int flat = it * 256 + tid;
    sA[AIDX(flat >> 7, flat & 127)] = sg[flat];
  }
  __syncthreads();

  // Cholesky, right-looking, column-owner trailing update (parity-split rows)
  for (int c = 0; c < D; ++c) {
    if (tid == 0) sA[AIDX(c, c)] = sqrtf(sA[AIDX(c, c)]);
    __syncthreads();
    if (tid < D && tid > c) sA[AIDX(tid, c)] /= sA[AIDX(c, c)];
    __syncthreads();
    int e = tid & 127, par = tid >> 7;
    if (e > c) {
      float aec = sA[AIDX(e, c)];
      for (int r = c + 1 + par; r < D; r += 2)
        if (r >= e) sA[AIDX(r, e)] -= sA[AIDX(r, c)] * aec;
    }
    __syncthreads();
  }

  // triangular inverse: row-serial, column-parallel
  for (int i = 1; i < D; ++i) {
    if (tid < i) {
      int c = tid;
      float s = sA[AIDX(i, c)] * (1.0f / sA[AIDX(c, c)]);  // m=c term (T[c][c]=1/Lcc)
      for (int m = c + 1; m < i; ++m) s += sA[AIDX(i, m)] * sA[AIDX(c, m)];
      sA[AIDX(c, i)] = -s / sA[AIDX(i, i)];
    }
    __syncthreads();
  }

  // w = T * mu_k
  const float* muk = mu + k * D;
  if (tid < D) {
    int i = tid;
    float s = (1.0f / sA[AIDX(i, i)]) * muk[i];
    for (int j = 0; j < i; ++j) s += sA[AIDX(j, i)] * muk[j];
    wv[k * D + i] = s;
  }

  // Tt[k][d][i] = T[i][d] for d<=i else 0  (contraction-major for pass 5)
  for (int it = 0; it < 64; ++it) {
    int flat = it * 256 + tid;
    int d = flat >> 7, i = flat & 127;
    float v = 0.f;
    if (d == i) v = 1.0f / sA[AIDX(d, d)];
    else if (d < i) v = sA[AIDX(d, i)];
    Tt[((size_t)k << 14) + flat] = v;
  }

  // logdet(2*pi*Sigma) and coef; reuse sA[4..7] as scratch after sync
  __syncthreads();
  float lv = (tid < D) ? logf(sA[AIDX(tid, tid)]) : 0.f;
#pragma unroll
  for (int off = 1; off < 64; off <<= 1) lv += __shfl_xor(lv, off);
  if ((tid & 63) == 0) sA[4 + (tid >> 6)] = lv;
  __syncthreads();
  if (tid == 0) {
    float sl = sA[4] + sA[5] + sA[6] + sA[7];
    float logdet = (float)D * LOG_2PI + 2.0f * sl;
    coef[k] = logf(Nk[k] * (1.0f / (float)S_LEN)) - 0.5f * logdet;
  }
#undef AIDX
}

// ---------------------------------------------------------------- pass 5
__global__ __launch_bounds__(256, 2) void k_maha(const float* __restrict__ x,
                                                 const float* __restrict__ Tt,
                                                 const float* __restrict__ wv,
                                                 const float* __restrict__ coef,
                                                 float* __restrict__ epart) {
  __shared__ float xt[D][MBLK];    // transposed x chunk: 32 KB
  __shared__ float tt[32][D];      // 16 KB d-tile of T^T
  __shared__ float wl[K][D];       // 4 KB
  __shared__ float cfl[K];
  __shared__ float red[2][16][4];
  int tid = threadIdx.x;
  int bs = blockIdx.x * MBLK;

  {  // stage x chunk transposed
    int s = tid & 63;
    int fbase = tid >> 6;
    for (int it = 0; it < 8; ++it) {
      int f = fbase + it * 4;   // 0..31
      float4 v = *(const float4*)(x + (size_t)(bs + s) * D + f * 4);
      xt[f * 4 + 0][s] = v.x;
      xt[f * 4 + 1][s] = v.y;
      xt[f * 4 + 2][s] = v.z;
      xt[f * 4 + 3][s] = v.w;
    }
  }
  for (int it = 0; it < 4; ++it) {
    int idx = it * 256 + tid;
    wl[idx >> 7][idx & 127] = wv[idx];
  }
  if (tid < K) cfl[tid] = coef[tid];

  int w = tid >> 6, l = tid & 63;
  int sgg = ((w >> 1) << 3) + (l >> 3);   // 0..15, 4 samples each
  int tig = ((w & 1) << 3) + (l & 7);     // 0..15, 8 y-dims each
  int s0 = sgg * 4, i0 = tig * 8;

  // online log-sum-exp state (per sample, held by tid<MBLK lanes)
  float mrun = -1e30f, srun = 0.f;
  for (int k = 0; k < K; ++k) {
    float acc[4][8] = {};
    for (int dt = 0; dt < 4; ++dt) {
      __syncthreads();   // tt free (and first iter: staging done)
      for (int it = 0; it < 4; ++it) {
        int f = it * 256 + tid;
        int dr = f >> 5, c4 = f & 31;
        *(float4*)&tt[dr][c4 * 4] =
            *(const float4*)(Tt + ((size_t)k << 14) + (size_t)(dt * 32 + dr) * D + c4 * 4);
      }
      __syncthreads();   // tt staged
#pragma unroll 4
      for (int d = 0; d < 32; ++d) {
        float4 xv = *(const float4*)&xt[dt * 32 + d][s0];
        float4 ta = *(const float4*)&tt[d][i0];
        float4 tb = *(const float4*)&tt[d][i0 + 4];
        float xa[4] = {xv.x, xv.y, xv.z, xv.w};
        float tv[8] = {ta.x, ta.y, ta.z, ta.w, tb.x, tb.y, tb.z, tb.w};
#pragma unroll
        for (int si = 0; si < 4; ++si)
#pragma unroll
          for (int yi = 0; yi < 8; ++yi) acc[si][yi] += xa[si] * tv[yi];
      }
    }
    // maha partials: sum over this thread's 8 y-dims of (y - w)^2
    float4 wa = *(const float4*)&wl[k][i0];
    float4 wb = *(const float4*)&wl[k][i0 + 4];
    float wloc[8] = {wa.x, wa.y, wa.z, wa.w, wb.x, wb.y, wb.z, wb.w};
    float part[4];
#pragma unroll
    for (int si = 0; si < 4; ++si) {
      float s = 0.f;
#pragma unroll
      for (int yi = 0; yi < 8; ++yi) {
        float d2 = acc[si][yi] - wloc[yi];
        s += d2 * d2;
      }
      part[si] = s;
    }
#pragma unroll
    for (int si = 0; si < 4; ++si) {
      part[si] += __shfl_xor(part[si], 1);
      part[si] += __shfl_xor(part[si], 2);
      part[si] += __shfl_xor(part[si], 4);
    }
    if ((l & 7) == 0) {
#pragma unroll
      for (int si = 0; si < 4; ++si) red[w & 1][sgg][si] = part[si];
    }
    __syncthreads();
    if (tid < MBLK) {
      float maha = red[0][tid >> 2][tid & 3] + red[1][tid >> 2][tid & 3];
      float a = cfl[k] - 0.5f * maha;
      // online LSE update: logdens = mrun + log(srun) at the end
      if (a > mrun) {
        srun = srun * expf(mrun - a) + 1.0f;
        mrun = a;
      } else {
        srun += expf(a - mrun);
      }
    }
  }
  if (tid < MBLK) {
    float v = mrun + logf(srun);
#pragma unroll
    for (int off = 1; off < 64; off <<= 1) v += __shfl_xor(v, off);
    if (tid == 0) epart[blockIdx.x] = v;
  }
}

// ---------------------------------------------------------------- pass 6
__global__ __launch_bounds__(256) void k_final(const float* __restrict__ epart,
                                               float* __restrict__ out) {
  __shared__ double sw[4];
  int tid = threadIdx.x;
  double a = 0.0;
  for (int it = 0; it < NMB / 256; ++it) a += (double)epart[it * 256 + tid];
#pragma unroll
  for (int off = 1; off < 64; off <<= 1) a += __shfl_xor(a, off);
  if ((tid & 63) == 0) sw[tid >> 6] = a;
  __syncthreads();
  if (tid == 0) out[0] = (float)(-(sw[0] + sw[1] + sw[2] + sw[3]));
}

// ----------------------------------------------------------------
extern "C" void kernel_launch(void* const* d_in, const int* in_sizes, int n_in,
                              void* d_out, int out_size, void* d_ws, size_t ws_size,
                              hipStream_t stream) {
  (void)in_sizes; (void)n_in; (void)out_size; (void)ws_size;
  const float* x = (const float*)d_in[0];
  const float* W = (const float*)d_in[1];
  const float* b = (const float*)d_in[2];
  float* out = (float*)d_out;
  float* ws = (float*)d_ws;

  float* gamma = ws + OFF_GAMMA;
  float* m2p   = ws + OFF_M2P;
  float* msp   = ws + OFF_MSP;
  float* nkp   = ws + OFF_NKP;
  float* Nk    = ws + OFF_NK;
  float* mu    = ws + OFF_MU;
  float* sigma = ws + OFF_SIGMA;
  float* Tt    = ws + OFF_TT;
  float* wvp   = ws + OFF_WV;
  float* coefp = ws + OFF_COEF;
  float* epart = ws + OFF_EPART;

  k_gamma<<<S_LEN / 256, 256, 0, stream>>>(x, W, b, gamma);
  k_m2<<<dim3(NCHUNK, K), 256, 0, stream>>>(x, gamma, m2p, msp, nkp);
  k_redmu<<<1, 256, 0, stream>>>(msp, nkp, Nk, mu);
  k_sigma<<<dim3(64, K), 256, 0, stream>>>(m2p, Nk, mu, sigma);
  k_chol<<<K, 256, 0, stream>>>(sigma, Nk, mu, Tt, wvp, coefp);
  k_maha<<<NMB, 256, 0, stream>>>(x, Tt, wvp, coefp, epart);
  k_final<<<1, 256, 0, stream>>>(epart, out);
}

// Round 3
// 880.411 us; speedup vs baseline: 1.5974x; 1.5974x over previous
//
#include <hip/hip_runtime.h>

// GaussianMixture energy on MI355X — fp32 pipeline, round 3.
// S=65536 samples, D=128 dims, K=8 components.
//
// Pipeline:
//  1. k_gamma : gamma = softmax(x@W + b)            [S,K] -> ws
//  2. k_m2    : partial M2_k = X^T diag(g_k) X, partial musum, partial Nk
//  3. k_redmu : Nk, mu
//  4. k_sigma : sigma_k = M2_k/Nk - mu mu^T
//  5. k_inv   : B = sigma^{-1} via symmetric SWEEP operator (fully parallel),
//               v = B mu, coef_k = log(phi) - 0.5*logdet(2*pi*sigma)
//  6. k_maha  : y = x B ; maha = (x-mu).(y-v) ; per-sample log-sum-exp
//  7. k_final : energy = -sum
//
// Round-2->3: replaced the latency-serial k_chol (877us, 62% of runtime) with
// k_inv: sweep operator keeps the matrix symmetric, so every pivot step is a
// fully-parallel rank-1 update (256 threads x 16 float4 quads, bank-balanced),
// 2 barriers/iter, no serial dependent-LDS chains. logdet = sum log(pivots).

#define S_LEN 65536
#define D 128
#define K 8
#define NCHUNK 64                  // S-chunks in pass 2
#define CHUNK (S_LEN / NCHUNK)     // 1024 samples per m2 block
#define MBLK 64                    // samples per maha block
#define NMB (S_LEN / MBLK)         // 1024 blocks

// workspace layout (float offsets)
#define OFF_GAMMA 0
#define SZ_GAMMA (S_LEN * K)                       // 524288
#define OFF_M2P (OFF_GAMMA + SZ_GAMMA)
#define SZ_M2P (K * NCHUNK * D * D)                // 8388608
#define OFF_MSP (OFF_M2P + SZ_M2P)
#define SZ_MSP (K * NCHUNK * D)                    // 65536
#define OFF_NKP (OFF_MSP + SZ_MSP)
#define SZ_NKP (K * NCHUNK)                        // 512
#define OFF_NK (OFF_NKP + SZ_NKP)
#define OFF_MU (OFF_NK + K)
#define OFF_B (OFF_MU + K * D)
#define OFF_SIGMA (OFF_B + K * D * D)
#define OFF_WV (OFF_SIGMA + K * D * D)
#define OFF_COEF (OFF_WV + K * D)
#define OFF_EPART (OFF_COEF + K)
// total floats = OFF_EPART + NMB = 9244176  (~37 MB of d_ws)

#define LOG_2PI 1.8378770664093453f

// ---------------------------------------------------------------- pass 1
__global__ __launch_bounds__(256) void k_gamma(const float* __restrict__ x,
                                               const float* __restrict__ W,
                                               const float* __restrict__ b,
                                               float* __restrict__ gamma) {
  __shared__ float Wt[K][D];   // W transposed: Wt[k][d]
  __shared__ float bl[K];
  int tid = threadIdx.x;
  for (int it = 0; it < 4; ++it) {
    int idx = it * 256 + tid;           // 1024 = D*K
    Wt[idx & 7][idx >> 3] = W[idx];     // W is [D][K] row-major
  }
  if (tid < K) bl[tid] = b[tid];
  __syncthreads();

  int s = blockIdx.x * 256 + tid;
  float li[K];
#pragma unroll
  for (int k = 0; k < K; ++k) li[k] = bl[k];
  const float4* xr = (const float4*)(x + (size_t)s * D);
#pragma unroll 8
  for (int i = 0; i < 32; ++i) {
    float4 xv = xr[i];
#pragma unroll
    for (int k = 0; k < K; ++k) {
      float4 wv = *(const float4*)&Wt[k][i * 4];
      li[k] += xv.x * wv.x + xv.y * wv.y + xv.z * wv.z + xv.w * wv.w;
    }
  }
  float m = li[0];
#pragma unroll
  for (int k = 1; k < K; ++k) m = fmaxf(m, li[k]);
  float p[K];
  float sum = 0.f;
#pragma unroll
  for (int k = 0; k < K; ++k) { p[k] = expf(li[k] - m); sum += p[k]; }
  float inv = 1.0f / sum;
  float4 o0 = {p[0] * inv, p[1] * inv, p[2] * inv, p[3] * inv};
  float4 o1 = {p[4] * inv, p[5] * inv, p[6] * inv, p[7] * inv};
  *(float4*)(gamma + (size_t)s * K) = o0;
  *(float4*)(gamma + (size_t)s * K + 4) = o1;
}

// ---------------------------------------------------------------- pass 2
// per-block: one (k, chunk): M2 tile 128x128 in registers (8x8 per thread)
__global__ __launch_bounds__(256, 2) void k_m2(const float* __restrict__ x,
                                               const float* __restrict__ gamma,
                                               float* __restrict__ m2p,
                                               float* __restrict__ msp,
                                               float* __restrict__ nkp) {
  __shared__ float xs[16][D];
  __shared__ float wx[16][D];
  __shared__ float red16[16];
  int tid = threadIdx.x;
  int c = blockIdx.x, k = blockIdx.y;
  int s0b = c * CHUNK;

  // wave-remapped 16x16 thread-tile grid: within a wave, 8 distinct d-groups
  // x 8 distinct e-groups -> both LDS reads are <=2-way bank aliasing (free).
  int w = tid >> 6, l = tid & 63;
  int d0 = (((w >> 1) << 3) + (l >> 3)) * 8;
  int e0 = (((w & 1) << 3) + (l & 7)) * 8;

  float acc[8][8] = {};
  float msacc = 0.f, gacc = 0.f;
  int js = tid >> 4, ds = (tid & 15) * 8;

  for (int t = 0; t < CHUNK / 16; ++t) {
    int s0 = s0b + t * 16;
    float4 v0 = *(const float4*)(x + (size_t)(s0 + js) * D + ds);
    float4 v1 = *(const float4*)(x + (size_t)(s0 + js) * D + ds + 4);
    float g = gamma[(size_t)(s0 + js) * K + k];
    __syncthreads();   // previous tile's compute done
    *(float4*)&xs[js][ds] = v0;
    *(float4*)&xs[js][ds + 4] = v1;
    float4 w0 = {g * v0.x, g * v0.y, g * v0.z, g * v0.w};
    float4 w1 = {g * v1.x, g * v1.y, g * v1.z, g * v1.w};
    *(float4*)&wx[js][ds] = w0;
    *(float4*)&wx[js][ds + 4] = w1;
    if ((tid & 15) == 0) gacc += g;
    __syncthreads();   // tile staged
#pragma unroll 4
    for (int j = 0; j < 16; ++j) {
      float4 a0 = *(const float4*)&wx[j][d0];
      float4 a1 = *(const float4*)&wx[j][d0 + 4];
      float4 b0 = *(const float4*)&xs[j][e0];
      float4 b1 = *(const float4*)&xs[j][e0 + 4];
      float av[8] = {a0.x, a0.y, a0.z, a0.w, a1.x, a1.y, a1.z, a1.w};
      float bv[8] = {b0.x, b0.y, b0.z, b0.w, b1.x, b1.y, b1.z, b1.w};
#pragma unroll
      for (int di = 0; di < 8; ++di)
#pragma unroll
        for (int ei = 0; ei < 8; ++ei) acc[di][ei] += av[di] * bv[ei];
    }
    if (tid < D) {
#pragma unroll
      for (int j = 0; j < 16; ++j) msacc += wx[j][tid];
    }
  }

  size_t base = (size_t)(k * NCHUNK + c) * (D * D);
#pragma unroll
  for (int di = 0; di < 8; ++di) {
#pragma unroll
    for (int e4 = 0; e4 < 2; ++e4) {
      float4 o = {acc[di][e4 * 4 + 0], acc[di][e4 * 4 + 1],
                  acc[di][e4 * 4 + 2], acc[di][e4 * 4 + 3]};
      *(float4*)(m2p + base + (size_t)(d0 + di) * D + e0 + e4 * 4) = o;
    }
  }
  if (tid < D) msp[(size_t)(k * NCHUNK + c) * D + tid] = msacc;
  if ((tid & 15) == 0) red16[tid >> 4] = gacc;
  __syncthreads();
  if (tid == 0) {
    float s = 0.f;
    for (int i = 0; i < 16; ++i) s += red16[i];
    nkp[k * NCHUNK + c] = s;
  }
}

// ---------------------------------------------------------------- pass 3a
__global__ __launch_bounds__(256) void k_redmu(const float* __restrict__ msp,
                                               const float* __restrict__ nkp,
                                               float* __restrict__ Nk,
                                               float* __restrict__ mu) {
  __shared__ float sNk[K];
  int tid = threadIdx.x;
  if (tid < K) {
    float s = 0.f;
    for (int c = 0; c < NCHUNK; ++c) s += nkp[tid * NCHUNK + c];
    sNk[tid] = s;
    Nk[tid] = s;
  }
  __syncthreads();
  for (int it = 0; it < (K * D) / 256; ++it) {
    int idx = it * 256 + tid;
    int k = idx >> 7;
    float s = 0.f;
    for (int c = 0; c < NCHUNK; ++c) s += msp[(size_t)(k * NCHUNK + c) * D + (idx & 127)];
    mu[idx] = s / sNk[k];
  }
}

// ---------------------------------------------------------------- pass 3b
__global__ __launch_bounds__(256) void k_sigma(const float* __restrict__ m2p,
                                               const float* __restrict__ Nk,
                                               const float* __restrict__ mu,
                                               float* __restrict__ sigma) {
  int tid = threadIdx.x;
  int k = blockIdx.y;
  int flat = blockIdx.x * 256 + tid;
  int d = flat >> 7, e = flat & 127;
  float s = 0.f;
  for (int c = 0; c < NCHUNK; ++c) s += m2p[((size_t)(k * NCHUNK + c) << 14) + flat];
  sigma[((size_t)k << 14) + flat] = s / Nk[k] - mu[k * D + d] * mu[k * D + e];
}

// ---------------------------------------------------------------- pass 4
// One block per component: B = Sigma^{-1} via the SWEEP operator.
// Sweeping all 128 pivots of an SPD matrix yields -A^{-1} and PRESERVES
// SYMMETRY, so pivot column == pivot row: each step is a fully-parallel
// rank-1 update. Thread t owns 16 float4 quads: rows (t>>5)+8i, col-quad
// t&31 -- a wave covers all 32 col-strips -> bank-balanced b128 RMW.
// Pivots d_c are the Cholesky Schur diagonals (>0): logdet = sum log d_c.
__global__ __launch_bounds__(256) void k_inv(const float* __restrict__ sigma,
                                             const float* __restrict__ Nk,
                                             const float* __restrict__ mu,
                                             float* __restrict__ B,
                                             float* __restrict__ vv,
                                             float* __restrict__ coef) {
  __shared__ float A[D * D];   // row-major, 64 KB
  __shared__ float mus[D];
  int tid = threadIdx.x;
  int k = blockIdx.x;
  const float* sg = sigma + ((size_t)k << 14);
#pragma unroll
  for (int i = 0; i < 16; ++i) {
    int f = tid + 256 * i;
    *(float4*)&A[f << 2] = *(const float4*)&sg[f << 2];
  }
  if (tid < D) mus[tid] = mu[k * D + tid];
  __syncthreads();

  int ph = tid >> 5;    // row phase 0..7
  int c4 = tid & 31;    // column-quad strip
  float logdet = 0.f;

  for (int c = 0; c < D; ++c) {
    // ---- read phase: pivot row (= pivot column by symmetry) into registers
    float d = A[(c << 7) + c];
    float piv = 1.0f / d;
    logdet += logf(d);
    float4 rq = *(const float4*)&A[(c << 7) + (c4 << 2)];
    float cv[16];
#pragma unroll
    for (int i = 0; i < 16; ++i) cv[i] = A[(c << 7) + ph + 8 * i];
    __syncthreads();   // all reads of row c complete before any write

    float4 rfac = {piv * rq.x, piv * rq.y, piv * rq.z, piv * rq.w};
    int cq = c >> 2, cl = c & 3;
#pragma unroll
    for (int i = 0; i < 16; ++i) {
      int r = ph + 8 * i;
      float* ap = &A[(r << 7) + (c4 << 2)];
      float4 own = *(float4*)ap;
      bool pr = (r == c);
      float4 up;
      up.x = pr ? rfac.x : own.x - cv[i] * rfac.x;
      up.y = pr ? rfac.y : own.y - cv[i] * rfac.y;
      up.z = pr ? rfac.z : own.z - cv[i] * rfac.z;
      up.w = pr ? rfac.w : own.w - cv[i] * rfac.w;
      if (c4 == cq) {            // quad contains pivot column c
        float nv = pr ? -piv : cv[i] * piv;
        if (cl == 0) up.x = nv;          // cl is wave-uniform
        else if (cl == 1) up.y = nv;
        else if (cl == 2) up.z = nv;
        else up.w = nv;
      }
      *(float4*)ap = up;
    }
    __syncthreads();
  }

  // ---- outputs: B = -A (= Sigma^{-1}), v = B mu, coef
  size_t bbase = (size_t)k << 14;
#pragma unroll
  for (int i = 0; i < 16; ++i) {
    int f = tid + 256 * i;
    float4 a = *(const float4*)&A[f << 2];
    float4 o = {-a.x, -a.y, -a.z, -a.w};
    *(float4*)(B + bbase + ((size_t)f << 2)) = o;
  }
  if (tid < D) {
    float s = 0.f;
#pragma unroll 8
    for (int q = 0; q < 32; ++q) {
      float4 a = *(const float4*)&A[(tid << 7) + (q << 2)];
      float4 m = *(const float4*)&mus[q << 2];
      s += a.x * m.x + a.y * m.y + a.z * m.z + a.w * m.w;
    }
    vv[k * D + tid] = -s;
  }
  if (tid == 0)
    coef[k] = logf(Nk[k] * (1.0f / (float)S_LEN)) -
              0.5f * ((float)D * LOG_2PI + logdet);
}

// ---------------------------------------------------------------- pass 5
// y = x B_k (register-tiled GEMM), maha = (x-mu).(y-v), online LSE over k.
__global__ __launch_bounds__(256, 2) void k_maha(const float* __restrict__ x,
                                                 const float* __restrict__ B,
                                                 const float* __restrict__ vv,
                                                 const float* __restrict__ mu,
                                                 const float* __restrict__ coef,
                                                 float* __restrict__ epart) {
  __shared__ float xt[D][MBLK];    // transposed x chunk: 32 KB
  __shared__ float tt[32][D];      // 16 KB d-tile of B
  __shared__ float vl[K][D];       // 4 KB  v = B mu
  __shared__ float mul[K][D];      // 4 KB  mu
  __shared__ float cfl[K];
  __shared__ float red[2][16][4];
  int tid = threadIdx.x;
  int bs = blockIdx.x * MBLK;

  {  // stage x chunk transposed
    int s = tid & 63;
    int fbase = tid >> 6;
    for (int it = 0; it < 8; ++it) {
      int f = fbase + it * 4;   // 0..31
      float4 v = *(const float4*)(x + (size_t)(bs + s) * D + f * 4);
      xt[f * 4 + 0][s] = v.x;
      xt[f * 4 + 1][s] = v.y;
      xt[f * 4 + 2][s] = v.z;
      xt[f * 4 + 3][s] = v.w;
    }
  }
  for (int it = 0; it < 4; ++it) {
    int idx = it * 256 + tid;
    vl[idx >> 7][idx & 127] = vv[idx];
    mul[idx >> 7][idx & 127] = mu[idx];
  }
  if (tid < K) cfl[tid] = coef[tid];

  int w = tid >> 6, l = tid & 63;
  int sgg = ((w >> 1) << 3) + (l >> 3);   // 0..15, 4 samples each
  int tig = ((w & 1) << 3) + (l & 7);     // 0..15, 8 y-dims each
  int s0 = sgg * 4, i0 = tig * 8;

  // online log-sum-exp state (per sample, held by tid<MBLK lanes)
  float mrun = -1e30f, srun = 0.f;
  for (int k = 0; k < K; ++k) {
    float acc[4][8] = {};
    for (int dt = 0; dt < 4; ++dt) {
      __syncthreads();   // tt free (and first iter: staging done)
      for (int it = 0; it < 4; ++it) {
        int f = it * 256 + tid;
        int dr = f >> 5, c4 = f & 31;
        *(float4*)&tt[dr][c4 * 4] =
            *(const float4*)(B + ((size_t)k << 14) + (size_t)(dt * 32 + dr) * D + c4 * 4);
      }
      __syncthreads();   // tt staged
#pragma unroll 4
      for (int d = 0; d < 32; ++d) {
        float4 xv = *(const float4*)&xt[dt * 32 + d][s0];
        float4 ta = *(const float4*)&tt[d][i0];
        float4 tb = *(const float4*)&tt[d][i0 + 4];
        float xa[4] = {xv.x, xv.y, xv.z, xv.w};
        float tv[8] = {ta.x, ta.y, ta.z, ta.w, tb.x, tb.y, tb.z, tb.w};
#pragma unroll
        for (int si = 0; si < 4; ++si)
#pragma unroll
          for (int yi = 0; yi < 8; ++yi) acc[si][yi] += xa[si] * tv[yi];
      }
    }
    // maha partials: sum over this thread's 8 y-dims of (x-mu)*(y-v)
    float4 va = *(const float4*)&vl[k][i0];
    float4 vb = *(const float4*)&vl[k][i0 + 4];
    float4 ma = *(const float4*)&mul[k][i0];
    float4 mb = *(const float4*)&mul[k][i0 + 4];
    float vloc[8] = {va.x, va.y, va.z, va.w, vb.x, vb.y, vb.z, vb.w};
    float mloc[8] = {ma.x, ma.y, ma.z, ma.w, mb.x, mb.y, mb.z, mb.w};
    float part[4] = {0.f, 0.f, 0.f, 0.f};
#pragma unroll
    for (int yi = 0; yi < 8; ++yi) {
      float4 xq = *(const float4*)&xt[i0 + yi][s0];
      float xa[4] = {xq.x, xq.y, xq.z, xq.w};
#pragma unroll
      for (int si = 0; si < 4; ++si)
        part[si] += (xa[si] - mloc[yi]) * (acc[si][yi] - vloc[yi]);
    }
#pragma unroll
    for (int si = 0; si < 4; ++si) {
      part[si] += __shfl_xor(part[si], 1);
      part[si] += __shfl_xor(part[si], 2);
      part[si] += __shfl_xor(part[si], 4);
    }
    if ((l & 7) == 0) {
#pragma unroll
      for (int si = 0; si < 4; ++si) red[w & 1][sgg][si] = part[si];
    }
    __syncthreads();
    if (tid < MBLK) {
      float maha = red[0][tid >> 2][tid & 3] + red[1][tid >> 2][tid & 3];
      float a = cfl[k] - 0.5f * maha;
      if (a > mrun) {
        srun = srun * expf(mrun - a) + 1.0f;
        mrun = a;
      } else {
        srun += expf(a - mrun);
      }
    }
  }
  if (tid < MBLK) {
    float v = mrun + logf(srun);
#pragma unroll
    for (int off = 1; off < 64; off <<= 1) v += __shfl_xor(v, off);
    if (tid == 0) epart[blockIdx.x] = v;
  }
}

// ---------------------------------------------------------------- pass 6
__global__ __launch_bounds__(256) void k_final(const float* __restrict__ epart,
                                               float* __restrict__ out) {
  __shared__ double sw[4];
  int tid = threadIdx.x;
  double a = 0.0;
  for (int it = 0; it < NMB / 256; ++it) a += (double)epart[it * 256 + tid];
#pragma unroll
  for (int off = 1; off < 64; off <<= 1) a += __shfl_xor(a, off);
  if ((tid & 63) == 0) sw[tid >> 6] = a;
  __syncthreads();
  if (tid == 0) out[0] = (float)(-(sw[0] + sw[1] + sw[2] + sw[3]));
}

// ----------------------------------------------------------------
extern "C" void kernel_launch(void* const* d_in, const int* in_sizes, int n_in,
                              void* d_out, int out_size, void* d_ws, size_t ws_size,
                              hipStream_t stream) {
  (void)in_sizes; (void)n_in; (void)out_size; (void)ws_size;
  const float* x = (const float*)d_in[0];
  const float* W = (const float*)d_in[1];
  const float* b = (const float*)d_in[2];
  float* out = (float*)d_out;
  float* ws = (float*)d_ws;

  float* gamma = ws + OFF_GAMMA;
  float* m2p   = ws + OFF_M2P;
  float* msp   = ws + OFF_MSP;
  float* nkp   = ws + OFF_NKP;
  float* Nk    = ws + OFF_NK;
  float* mu    = ws + OFF_MU;
  float* Bm    = ws + OFF_B;
  float* sigma = ws + OFF_SIGMA;
  float* wvp   = ws + OFF_WV;
  float* coefp = ws + OFF_COEF;
  float* epart = ws + OFF_EPART;

  k_gamma<<<S_LEN / 256, 256, 0, stream>>>(x, W, b, gamma);
  k_m2<<<dim3(NCHUNK, K), 256, 0, stream>>>(x, gamma, m2p, msp, nkp);
  k_redmu<<<1, 256, 0, stream>>>(msp, nkp, Nk, mu);
  k_sigma<<<dim3(64, K), 256, 0, stream>>>(m2p, Nk, mu, sigma);
  k_inv<<<K, 256, 0, stream>>>(sigma, Nk, mu, Bm, wvp, coefp);
  k_maha<<<NMB, 256, 0, stream>>>(x, Bm, wvp, mu, coefp, epart);
  k_final<<<1, 256, 0, stream>>>(epart, out);
}

// Round 4
// 623.343 us; speedup vs baseline: 2.2562x; 1.4124x over previous
//
#include <hip/hip_runtime.h>

// GaussianMixture energy on MI355X — fp32 pipeline, round 4.
// S=65536 samples, D=128 dims, K=8 components.
//
// Pipeline:
//  1. k_gamma : gamma = softmax(x@W + b)            [S,K] -> ws
//  2. k_m2    : partial M2_k = X^T diag(g_k) X, partial musum, partial Nk
//  3. k_redmu : Nk, mu
//  4. k_sigma : sigma_k = M2_k/Nk - mu mu^T
//  5. k_inv   : B = sigma^{-1} via BLOCKED (rank-32) symmetric sweep,
//               v = B mu, coef_k = log(phi) - 0.5*logdet(2*pi*sigma)
//  6. k_maha  : y = x B ; maha = (x-mu).(y-v) ; per-sample log-sum-exp
//  7. k_final : energy = -sum
//
// Round-3->4: k_inv rank-1 sweep (128 latency-serial iters, 1.56M LDS bank
// conflicts, 353us) replaced by blocked sweep: per 32-block: mini-sweep of the
// 32x32 pivot (Pinv), Y = C*Pinv (small GEMM), A -= Y*R rank-32 update with the
// A-tile in registers. A is touched 4x instead of 128x. A stored with per-row
// quad rotation (c + 4*(r>>3)) & 127 to break column bank patterns.

#define S_LEN 65536
#define D 128
#define K 8
#define NCHUNK 64                  // S-chunks in pass 2
#define CHUNK (S_LEN / NCHUNK)     // 1024 samples per m2 block
#define MBLK 64                    // samples per maha block
#define NMB (S_LEN / MBLK)         // 1024 blocks

// workspace layout (float offsets)
#define OFF_GAMMA 0
#define SZ_GAMMA (S_LEN * K)                       // 524288
#define OFF_M2P (OFF_GAMMA + SZ_GAMMA)
#define SZ_M2P (K * NCHUNK * D * D)                // 8388608
#define OFF_MSP (OFF_M2P + SZ_M2P)
#define SZ_MSP (K * NCHUNK * D)                    // 65536
#define OFF_NKP (OFF_MSP + SZ_MSP)
#define SZ_NKP (K * NCHUNK)                        // 512
#define OFF_NK (OFF_NKP + SZ_NKP)
#define OFF_MU (OFF_NK + K)
#define OFF_B (OFF_MU + K * D)
#define OFF_SIGMA (OFF_B + K * D * D)
#define OFF_WV (OFF_SIGMA + K * D * D)
#define OFF_COEF (OFF_WV + K * D)
#define OFF_EPART (OFF_COEF + K)
// total floats = OFF_EPART + NMB = 9244176  (~37 MB of d_ws)

#define LOG_2PI 1.8378770664093453f

// ---------------------------------------------------------------- pass 1
__global__ __launch_bounds__(256) void k_gamma(const float* __restrict__ x,
                                               const float* __restrict__ W,
                                               const float* __restrict__ b,
                                               float* __restrict__ gamma) {
  __shared__ float Wt[K][D];   // W transposed: Wt[k][d]
  __shared__ float bl[K];
  int tid = threadIdx.x;
  for (int it = 0; it < 4; ++it) {
    int idx = it * 256 + tid;           // 1024 = D*K
    Wt[idx & 7][idx >> 3] = W[idx];     // W is [D][K] row-major
  }
  if (tid < K) bl[tid] = b[tid];
  __syncthreads();

  int s = blockIdx.x * 256 + tid;
  float li[K];
#pragma unroll
  for (int k = 0; k < K; ++k) li[k] = bl[k];
  const float4* xr = (const float4*)(x + (size_t)s * D);
#pragma unroll 8
  for (int i = 0; i < 32; ++i) {
    float4 xv = xr[i];
#pragma unroll
    for (int k = 0; k < K; ++k) {
      float4 wv = *(const float4*)&Wt[k][i * 4];
      li[k] += xv.x * wv.x + xv.y * wv.y + xv.z * wv.z + xv.w * wv.w;
    }
  }
  float m = li[0];
#pragma unroll
  for (int k = 1; k < K; ++k) m = fmaxf(m, li[k]);
  float p[K];
  float sum = 0.f;
#pragma unroll
  for (int k = 0; k < K; ++k) { p[k] = expf(li[k] - m); sum += p[k]; }
  float inv = 1.0f / sum;
  float4 o0 = {p[0] * inv, p[1] * inv, p[2] * inv, p[3] * inv};
  float4 o1 = {p[4] * inv, p[5] * inv, p[6] * inv, p[7] * inv};
  *(float4*)(gamma + (size_t)s * K) = o0;
  *(float4*)(gamma + (size_t)s * K + 4) = o1;
}

// ---------------------------------------------------------------- pass 2
// per-block: one (k, chunk): M2 tile 128x128 in registers (8x8 per thread)
__global__ __launch_bounds__(256, 2) void k_m2(const float* __restrict__ x,
                                               const float* __restrict__ gamma,
                                               float* __restrict__ m2p,
                                               float* __restrict__ msp,
                                               float* __restrict__ nkp) {
  __shared__ float xs[16][D];
  __shared__ float wx[16][D];
  __shared__ float red16[16];
  int tid = threadIdx.x;
  int c = blockIdx.x, k = blockIdx.y;
  int s0b = c * CHUNK;

  // wave-remapped 16x16 thread-tile grid: within a wave, 8 distinct d-groups
  // x 8 distinct e-groups -> both LDS reads are <=2-way bank aliasing (free).
  int w = tid >> 6, l = tid & 63;
  int d0 = (((w >> 1) << 3) + (l >> 3)) * 8;
  int e0 = (((w & 1) << 3) + (l & 7)) * 8;

  float acc[8][8] = {};
  float msacc = 0.f, gacc = 0.f;
  int js = tid >> 4, ds = (tid & 15) * 8;

  for (int t = 0; t < CHUNK / 16; ++t) {
    int s0 = s0b + t * 16;
    float4 v0 = *(const float4*)(x + (size_t)(s0 + js) * D + ds);
    float4 v1 = *(const float4*)(x + (size_t)(s0 + js) * D + ds + 4);
    float g = gamma[(size_t)(s0 + js) * K + k];
    __syncthreads();   // previous tile's compute done
    *(float4*)&xs[js][ds] = v0;
    *(float4*)&xs[js][ds + 4] = v1;
    float4 w0 = {g * v0.x, g * v0.y, g * v0.z, g * v0.w};
    float4 w1 = {g * v1.x, g * v1.y, g * v1.z, g * v1.w};
    *(float4*)&wx[js][ds] = w0;
    *(float4*)&wx[js][ds + 4] = w1;
    if ((tid & 15) == 0) gacc += g;
    __syncthreads();   // tile staged
#pragma unroll 4
    for (int j = 0; j < 16; ++j) {
      float4 a0 = *(const float4*)&wx[j][d0];
      float4 a1 = *(const float4*)&wx[j][d0 + 4];
      float4 b0 = *(const float4*)&xs[j][e0];
      float4 b1 = *(const float4*)&xs[j][e0 + 4];
      float av[8] = {a0.x, a0.y, a0.z, a0.w, a1.x, a1.y, a1.z, a1.w};
      float bv[8] = {b0.x, b0.y, b0.z, b0.w, b1.x, b1.y, b1.z, b1.w};
#pragma unroll
      for (int di = 0; di < 8; ++di)
#pragma unroll
        for (int ei = 0; ei < 8; ++ei) acc[di][ei] += av[di] * bv[ei];
    }
    if (tid < D) {
#pragma unroll
      for (int j = 0; j < 16; ++j) msacc += wx[j][tid];
    }
  }

  size_t base = (size_t)(k * NCHUNK + c) * (D * D);
#pragma unroll
  for (int di = 0; di < 8; ++di) {
#pragma unroll
    for (int e4 = 0; e4 < 2; ++e4) {
      float4 o = {acc[di][e4 * 4 + 0], acc[di][e4 * 4 + 1],
                  acc[di][e4 * 4 + 2], acc[di][e4 * 4 + 3]};
      *(float4*)(m2p + base + (size_t)(d0 + di) * D + e0 + e4 * 4) = o;
    }
  }
  if (tid < D) msp[(size_t)(k * NCHUNK + c) * D + tid] = msacc;
  if ((tid & 15) == 0) red16[tid >> 4] = gacc;
  __syncthreads();
  if (tid == 0) {
    float s = 0.f;
    for (int i = 0; i < 16; ++i) s += red16[i];
    nkp[k * NCHUNK + c] = s;
  }
}

// ---------------------------------------------------------------- pass 3a
__global__ __launch_bounds__(256) void k_redmu(const float* __restrict__ msp,
                                               const float* __restrict__ nkp,
                                               float* __restrict__ Nk,
                                               float* __restrict__ mu) {
  __shared__ float sNk[K];
  int tid = threadIdx.x;
  if (tid < K) {
    float s = 0.f;
    for (int c = 0; c < NCHUNK; ++c) s += nkp[tid * NCHUNK + c];
    sNk[tid] = s;
    Nk[tid] = s;
  }
  __syncthreads();
  for (int it = 0; it < (K * D) / 256; ++it) {
    int idx = it * 256 + tid;
    int k = idx >> 7;
    float s = 0.f;
    for (int c = 0; c < NCHUNK; ++c) s += msp[(size_t)(k * NCHUNK + c) * D + (idx & 127)];
    mu[idx] = s / sNk[k];
  }
}

// ---------------------------------------------------------------- pass 3b
__global__ __launch_bounds__(256) void k_sigma(const float* __restrict__ m2p,
                                               const float* __restrict__ Nk,
                                               const float* __restrict__ mu,
                                               float* __restrict__ sigma) {
  int tid = threadIdx.x;
  int k = blockIdx.y;
  int flat = blockIdx.x * 256 + tid;
  int d = flat >> 7, e = flat & 127;
  float s = 0.f;
  for (int c = 0; c < NCHUNK; ++c) s += m2p[((size_t)(k * NCHUNK + c) << 14) + flat];
  sigma[((size_t)k << 14) + flat] = s / Nk[k] - mu[k * D + d] * mu[k * D + e];
}

// ---------------------------------------------------------------- pass 4
// One block per component: B = Sigma^{-1} via BLOCKED symmetric sweep.
// 4 outer steps (32-wide pivot blocks). Per step:
//   stage Pb (pivot block), Rb (row panel), Cb (col panel, transposed)
//   mini-sweep Pb (32 rank-1 steps on 32x32)   -> Pb = -P^{-1}, logdet += sum log d
//   Y-GEMM:   Yt[m][r] = (C * Pinv)[r][m]      (128x32x32)
//   big GEMM: A -= Y * R                       (128x128x32, tile in registers)
//   panel overwrite: col<-Y, row<-Y^T, pivot<-Pb
// A stored with per-row quad rotation to break 512B-stride bank patterns.
#define PBW 36
#define YTW 132
#define AROT(r, c) (((r) << 7) + ((((c) + (((r) >> 3) << 2))) & 127))

__global__ __launch_bounds__(256) void k_inv(const float* __restrict__ sigma,
                                             const float* __restrict__ Nk,
                                             const float* __restrict__ mu,
                                             float* __restrict__ B,
                                             float* __restrict__ vv,
                                             float* __restrict__ coef) {
  __shared__ float A[D * D];       // rotated row-major, 64 KB
  __shared__ float Pb[32 * PBW];   // pivot block (padded)
  __shared__ float Cb[32 * 128];   // col panel transposed: Cb[n][i] = A[i][tb+n]
  __shared__ float Yt[32 * YTW];   // Y transposed: Yt[m][r] = Y[r][m]
  __shared__ float Rb[32 * 128];   // row panel copy: Rb[m][j] = A[tb+m][j]
  __shared__ float mus[D];
  int tid = threadIdx.x;
  int k = blockIdx.x;
  const float* sg = sigma + ((size_t)k << 14);

  // load A (rotated)
#pragma unroll
  for (int i = 0; i < 16; ++i) {
    int f = tid + 256 * i;               // quad index 0..4095
    int r = f >> 5, c4 = (f & 31) << 2;
    *(float4*)&A[AROT(r, c4)] = *(const float4*)&sg[((size_t)f) << 2];
  }
  if (tid < D) mus[tid] = mu[k * D + tid];
  __syncthreads();

  float ldet = 0.f;

  // thread mappings
  int mr = tid >> 3, mq = tid & 7;            // mini-sweep / Pb staging: 32x8
  int ci = tid >> 1, ch = tid & 1;            // Cb staging / col panel: 128x2
  int w = tid >> 6, l = tid & 63;             // big GEMM wave-remap (as k_m2)
  int d0 = (((w >> 1) << 3) + (l >> 3)) * 8;
  int e0 = (((w & 1) << 3) + (l & 7)) * 8;

  for (int t = 0; t < 4; ++t) {
    int tb = t * 32;

    // ---- stage Pb, Rb, Cb from A
    *(float4*)&Pb[mr * PBW + 4 * mq] = *(const float4*)&A[AROT(tb + mr, tb + 4 * mq)];
#pragma unroll
    for (int q = 0; q < 4; ++q) {
      int f = tid + 256 * q;               // 1024 quads of the 32x128 row panel
      int rr = f >> 5, cc4 = (f & 31) << 2;
      *(float4*)&Rb[rr * 128 + cc4] = *(const float4*)&A[AROT(tb + rr, cc4)];
    }
#pragma unroll
    for (int n4 = 0; n4 < 4; ++n4) {
      float4 q4 = *(const float4*)&A[AROT(ci, tb + 16 * ch + 4 * n4)];
      int nb = 16 * ch + 4 * n4;
      Cb[(nb + 0) * 128 + ci] = q4.x;
      Cb[(nb + 1) * 128 + ci] = q4.y;
      Cb[(nb + 2) * 128 + ci] = q4.z;
      Cb[(nb + 3) * 128 + ci] = q4.w;
    }
    __syncthreads();

    // ---- mini-sweep Pb (32 rank-1 sweeps) -> Pb = -P^{-1}
    for (int c = 0; c < 32; ++c) {
      float dpv = Pb[c * PBW + c];
      float piv = 1.0f / dpv;
      ldet += logf(dpv);
      float4 rq = *(const float4*)&Pb[c * PBW + 4 * mq];
      float cv = Pb[mr * PBW + c];
      __syncthreads();   // reads of row c done
      float4 rfac = {piv * rq.x, piv * rq.y, piv * rq.z, piv * rq.w};
      float4 own = *(const float4*)&Pb[mr * PBW + 4 * mq];
      bool pr = (mr == c);
      float4 up;
      up.x = pr ? rfac.x : own.x - cv * rfac.x;
      up.y = pr ? rfac.y : own.y - cv * rfac.y;
      up.z = pr ? rfac.z : own.z - cv * rfac.z;
      up.w = pr ? rfac.w : own.w - cv * rfac.w;
      int cq = c >> 2, cl = c & 3;  // cl uniform
      if (mq == cq) {
        float nv = pr ? -piv : cv * piv;
        if (cl == 0) up.x = nv;
        else if (cl == 1) up.y = nv;
        else if (cl == 2) up.z = nv;
        else up.w = nv;
      }
      *(float4*)&Pb[mr * PBW + 4 * mq] = up;
      __syncthreads();
    }

    // ---- Y-GEMM: Yt[m][r] = sum_n Cb[n][r] * Pinv[n][m],  Pinv = -Pb
    {
      int rs = tid >> 3, cs = tid & 7;    // rows 4rs..+3, cols 4cs..+3
      float accY[4][4] = {};
#pragma unroll 8
      for (int n = 0; n < 32; ++n) {
        float4 cq4 = *(const float4*)&Cb[n * 128 + 4 * rs];
        float4 pq = *(const float4*)&Pb[n * PBW + 4 * cs];
        float ca[4] = {cq4.x, cq4.y, cq4.z, cq4.w};
        float pa[4] = {pq.x, pq.y, pq.z, pq.w};
#pragma unroll
        for (int q = 0; q < 4; ++q)
#pragma unroll
          for (int j = 0; j < 4; ++j) accY[q][j] -= ca[q] * pa[j];
      }
#pragma unroll
      for (int j = 0; j < 4; ++j) {
        float4 o = {accY[0][j], accY[1][j], accY[2][j], accY[3][j]};
        *(float4*)&Yt[(4 * cs + j) * YTW + 4 * rs] = o;
      }
    }
    __syncthreads();

    // ---- big GEMM: A[i][j] -= sum_m Y[i][m] * Rb[m][j]   (tile in registers)
    {
      float acc[8][8];
#pragma unroll
      for (int di = 0; di < 8; ++di) {
#pragma unroll
        for (int e4 = 0; e4 < 2; ++e4) {
          float4 a = *(const float4*)&A[AROT(d0 + di, e0 + 4 * e4)];
          acc[di][e4 * 4 + 0] = a.x; acc[di][e4 * 4 + 1] = a.y;
          acc[di][e4 * 4 + 2] = a.z; acc[di][e4 * 4 + 3] = a.w;
        }
      }
#pragma unroll 4
      for (int m = 0; m < 32; ++m) {
        float4 ya = *(const float4*)&Yt[m * YTW + d0];
        float4 yb = *(const float4*)&Yt[m * YTW + d0 + 4];
        float4 ra = *(const float4*)&Rb[m * 128 + e0];
        float4 rb2 = *(const float4*)&Rb[m * 128 + e0 + 4];
        float av[8] = {ya.x, ya.y, ya.z, ya.w, yb.x, yb.y, yb.z, yb.w};
        float bv[8] = {ra.x, ra.y, ra.z, ra.w, rb2.x, rb2.y, rb2.z, rb2.w};
#pragma unroll
        for (int di = 0; di < 8; ++di)
#pragma unroll
          for (int ei = 0; ei < 8; ++ei) acc[di][ei] -= av[di] * bv[ei];
      }
#pragma unroll
      for (int di = 0; di < 8; ++di) {
#pragma unroll
        for (int e4 = 0; e4 < 2; ++e4) {
          float4 o = {acc[di][e4 * 4 + 0], acc[di][e4 * 4 + 1],
                      acc[di][e4 * 4 + 2], acc[di][e4 * 4 + 3]};
          *(float4*)&A[AROT(d0 + di, e0 + 4 * e4)] = o;
        }
      }
    }
    __syncthreads();

    // ---- panel overwrite phase A: row panel (all cols) + col panel (i not in tb)
#pragma unroll
    for (int qq = 0; qq < 4; ++qq) {
      int j0 = 4 * mq + 32 * qq;
      *(float4*)&A[AROT(tb + mr, j0)] = *(const float4*)&Yt[mr * YTW + j0];
    }
    if (ci < tb || ci >= tb + 32) {
#pragma unroll
      for (int n = 0; n < 16; ++n) {
        int mloc = 16 * ch + ((n + ci) & 15);   // rotated order: spread banks
        A[AROT(ci, tb + mloc)] = Yt[mloc * YTW + ci];
      }
    }
    __syncthreads();
    // ---- phase B: pivot block <- Pb (= -P^{-1})
    *(float4*)&A[AROT(tb + mr, tb + 4 * mq)] = *(const float4*)&Pb[mr * PBW + 4 * mq];
    __syncthreads();
  }

  // ---- outputs: B = -A (= Sigma^{-1}), v = B mu, coef
  size_t bbase = (size_t)k << 14;
#pragma unroll
  for (int i = 0; i < 16; ++i) {
    int f = tid + 256 * i;
    int r = f >> 5, c4 = (f & 31) << 2;
    float4 a = *(const float4*)&A[AROT(r, c4)];
    float4 o = {-a.x, -a.y, -a.z, -a.w};
    *(float4*)(B + bbase + ((size_t)f << 2)) = o;
  }
  if (tid < D) {
    float s = 0.f;
#pragma unroll 8
    for (int q = 0; q < 32; ++q) {
      float4 a = *(const float4*)&A[AROT(tid, q << 2)];
      float4 m = *(const float4*)&mus[q << 2];
      s += a.x * m.x + a.y * m.y + a.z * m.z + a.w * m.w;
    }
    vv[k * D + tid] = -s;
  }
  if (tid == 0)
    coef[k] = logf(Nk[k] * (1.0f / (float)S_LEN)) -
              0.5f * ((float)D * LOG_2PI + ldet);
}

// ---------------------------------------------------------------- pass 5
// y = x B_k (register-tiled GEMM), maha = (x-mu).(y-v), online LSE over k.
__global__ __launch_bounds__(256, 2) void k_maha(const float* __restrict__ x,
                                                 const float* __restrict__ B,
                                                 const float* __restrict__ vv,
                                                 const float* __restrict__ mu,
                                                 const float* __restrict__ coef,
                                                 float* __restrict__ epart) {
  __shared__ float xt[D][MBLK];    // transposed x chunk: 32 KB
  __shared__ float tt[32][D];      // 16 KB d-tile of B
  __shared__ float vl[K][D];       // 4 KB  v = B mu
  __shared__ float mul[K][D];      // 4 KB  mu
  __shared__ float cfl[K];
  __shared__ float red[2][16][4];
  int tid = threadIdx.x;
  int bs = blockIdx.x * MBLK;

  {  // stage x chunk transposed
    int s = tid & 63;
    int fbase = tid >> 6;
    for (int it = 0; it < 8; ++it) {
      int f = fbase + it * 4;   // 0..31
      float4 v = *(const float4*)(x + (size_t)(bs + s) * D + f * 4);
      xt[f * 4 + 0][s] = v.x;
      xt[f * 4 + 1][s] = v.y;
      xt[f * 4 + 2][s] = v.z;
      xt[f * 4 + 3][s] = v.w;
    }
  }
  for (int it = 0; it < 4; ++it) {
    int idx = it * 256 + tid;
    vl[idx >> 7][idx & 127] = vv[idx];
    mul[idx >> 7][idx & 127] = mu[idx];
  }
  if (tid < K) cfl[tid] = coef[tid];

  int w = tid >> 6, l = tid & 63;
  int sgg = ((w >> 1) << 3) + (l >> 3);   // 0..15, 4 samples each
  int tig = ((w & 1) << 3) + (l & 7);     // 0..15, 8 y-dims each
  int s0 = sgg * 4, i0 = tig * 8;

  // online log-sum-exp state (per sample, held by tid<MBLK lanes)
  float mrun = -1e30f, srun = 0.f;
  for (int k = 0; k < K; ++k) {
    float acc[4][8] = {};
    for (int dt = 0; dt < 4; ++dt) {
      __syncthreads();   // tt free (and first iter: staging done)
      for (int it = 0; it < 4; ++it) {
        int f = it * 256 + tid;
        int dr = f >> 5, c4 = f & 31;
        *(float4*)&tt[dr][c4 * 4] =
            *(const float4*)(B + ((size_t)k << 14) + (size_t)(dt * 32 + dr) * D + c4 * 4);
      }
      __syncthreads();   // tt staged
#pragma unroll 4
      for (int d = 0; d < 32; ++d) {
        float4 xv = *(const float4*)&xt[dt * 32 + d][s0];
        float4 ta = *(const float4*)&tt[d][i0];
        float4 tb = *(const float4*)&tt[d][i0 + 4];
        float xa[4] = {xv.x, xv.y, xv.z, xv.w};
        float tv[8] = {ta.x, ta.y, ta.z, ta.w, tb.x, tb.y, tb.z, tb.w};
#pragma unroll
        for (int si = 0; si < 4; ++si)
#pragma unroll
          for (int yi = 0; yi < 8; ++yi) acc[si][yi] += xa[si] * tv[yi];
      }
    }
    // maha partials: sum over this thread's 8 y-dims of (x-mu)*(y-v)
    float4 va = *(const float4*)&vl[k][i0];
    float4 vb = *(const float4*)&vl[k][i0 + 4];
    float4 ma = *(const float4*)&mul[k][i0];
    float4 mb = *(const float4*)&mul[k][i0 + 4];
    float vloc[8] = {va.x, va.y, va.z, va.w, vb.x, vb.y, vb.z, vb.w};
    float mloc[8] = {ma.x, ma.y, ma.z, ma.w, mb.x, mb.y, mb.z, mb.w};
    float part[4] = {0.f, 0.f, 0.f, 0.f};
#pragma unroll
    for (int yi = 0; yi < 8; ++yi) {
      float4 xq = *(const float4*)&xt[i0 + yi][s0];
      float xa[4] = {xq.x, xq.y, xq.z, xq.w};
#pragma unroll
      for (int si = 0; si < 4; ++si)
        part[si] += (xa[si] - mloc[yi]) * (acc[si][yi] - vloc[yi]);
    }
#pragma unroll
    for (int si = 0; si < 4; ++si) {
      part[si] += __shfl_xor(part[si], 1);
      part[si] += __shfl_xor(part[si], 2);
      part[si] += __shfl_xor(part[si], 4);
    }
    if ((l & 7) == 0) {
#pragma unroll
      for (int si = 0; si < 4; ++si) red[w & 1][sgg][si] = part[si];
    }
    __syncthreads();
    if (tid < MBLK) {
      float maha = red[0][tid >> 2][tid & 3] + red[1][tid >> 2][tid & 3];
      float a = cfl[k] - 0.5f * maha;
      if (a > mrun) {
        srun = srun * expf(mrun - a) + 1.0f;
        mrun = a;
      } else {
        srun += expf(a - mrun);
      }
    }
  }
  if (tid < MBLK) {
    float v = mrun + logf(srun);
#pragma unroll
    for (int off = 1; off < 64; off <<= 1) v += __shfl_xor(v, off);
    if (tid == 0) epart[blockIdx.x] = v;
  }
}

// ---------------------------------------------------------------- pass 6
__global__ __launch_bounds__(256) void k_final(const float* __restrict__ epart,
                                               float* __restrict__ out) {
  __shared__ double sw[4];
  int tid = threadIdx.x;
  double a = 0.0;
  for (int it = 0; it < NMB / 256; ++it) a += (double)epart[it * 256 + tid];
#pragma unroll
  for (int off = 1; off < 64; off <<= 1) a += __shfl_xor(a, off);
  if ((tid & 63) == 0) sw[tid >> 6] = a;
  __syncthreads();
  if (tid == 0) out[0] = (float)(-(sw[0] + sw[1] + sw[2] + sw[3]));
}

// ----------------------------------------------------------------
extern "C" void kernel_launch(void* const* d_in, const int* in_sizes, int n_in,
                              void* d_out, int out_size, void* d_ws, size_t ws_size,
                              hipStream_t stream) {
  (void)in_sizes; (void)n_in; (void)out_size; (void)ws_size;
  const float* x = (const float*)d_in[0];
  const float* W = (const float*)d_in[1];
  const float* b = (const float*)d_in[2];
  float* out = (float*)d_out;
  float* ws = (float*)d_ws;

  float* gamma = ws + OFF_GAMMA;
  float* m2p   = ws + OFF_M2P;
  float* msp   = ws + OFF_MSP;
  float* nkp   = ws + OFF_NKP;
  float* Nk    = ws + OFF_NK;
  float* mu    = ws + OFF_MU;
  float* Bm    = ws + OFF_B;
  float* sigma = ws + OFF_SIGMA;
  float* wvp   = ws + OFF_WV;
  float* coefp = ws + OFF_COEF;
  float* epart = ws + OFF_EPART;

  k_gamma<<<S_LEN / 256, 256, 0, stream>>>(x, W, b, gamma);
  k_m2<<<dim3(NCHUNK, K), 256, 0, stream>>>(x, gamma, m2p, msp, nkp);
  k_redmu<<<1, 256, 0, stream>>>(msp, nkp, Nk, mu);
  k_sigma<<<dim3(64, K), 256, 0, stream>>>(m2p, Nk, mu, sigma);
  k_inv<<<K, 256, 0, stream>>>(sigma, Nk, mu, Bm, wvp, coefp);
  k_maha<<<NMB, 256, 0, stream>>>(x, Bm, wvp, mu, coefp, epart);
  k_final<<<1, 256, 0, stream>>>(epart, out);
}

// Round 6
// 337.242 us; speedup vs baseline: 4.1703x; 1.8484x over previous
//
#include <hip/hip_runtime.h>

// GaussianMixture energy on MI355X — round 5: bf16-MFMA for both big GEMMs.
// S=65536, D=128, K=8.
//
// Pipeline:
//  1. k_gamma : gamma = softmax(x@W + b) -> gamma-transposed gt[S/64][8][64]
//  2. k_xprep : bf16 copies of x: xb[S][128] row-major, xt[S/64][128][64] chunk-transposed
//  3. k_m2    : M2_k = (sqrt(g) x)^T (sqrt(g) x) via mfma_f32_16x16x32_bf16; msp, nkp
//  4. k_redmu : Nk, mu
//  5. k_sigma : sigma_k = M2_k/Nk - mu mu^T   (fp32)
//  6. k_inv   : blocked symmetric sweep -> Sigma^{-1} (bf16 out), v=Sigma^{-1}mu,
//               c2=mu.v, coef
//  7. k_maha  : y = x Sigma^{-1} via MFMA (B symmetric -> no transpose);
//               maha = sum x*(y-2v)+c2; online LSE over k
//  8. k_final : energy = -sum
//
// All LDS tiles XOR-swizzled on 16B units so MFMA fragment ds_read_b128 are
// <=2-way bank aliased (free). Single-bf16 precision (threshold is +inf; the
// fp32 reference itself is +inf from density underflow).

#define S_LEN 65536
#define D 128
#define K 8
#define NCH 32                    // k_m2 S-chunks (2048 samples each)
#define KSTEP 64                  // samples per xt chunk / MFMA K-tile pair
#define NXTCH (S_LEN / KSTEP)     // 1024
#define MB_S 128                  // k_maha samples per block
#define NMB (S_LEN / MB_S)        // 512

// workspace layout (float offsets)
#define OFF_GT 0
#define SZ_GT (NXTCH * K * KSTEP)            // 524288
#define OFF_M2P (OFF_GT + SZ_GT)
#define SZ_M2P (K * NCH * D * D)             // 4194304
#define OFF_MSP (OFF_M2P + SZ_M2P)
#define SZ_MSP (K * NCH * D)                 // 32768
#define OFF_NKP (OFF_MSP + SZ_MSP)
#define SZ_NKP (K * NCH)                     // 256
#define OFF_NK (OFF_NKP + SZ_NKP)
#define OFF_MU (OFF_NK + 8)
#define OFF_SIGMA (OFF_MU + K * D)
#define OFF_WV (OFF_SIGMA + K * D * D)
#define OFF_COEF (OFF_WV + K * D)
#define OFF_C2 (OFF_COEF + 8)
#define OFF_EPART (OFF_C2 + 8)
#define OFF_XB (OFF_EPART + NMB)             // bf16: S*128 shorts = 4194304 floats
#define SZ_XB (S_LEN * D / 2)
#define OFF_XT (OFF_XB + SZ_XB)
#define SZ_XT (S_LEN * D / 2)
#define OFF_BH (OFF_XT + SZ_XT)              // bf16 Sigma^{-1}: 65536 floats
// total ~13.3M floats (~53 MB)

#define LOG_2PI 1.8378770664093453f

typedef __attribute__((ext_vector_type(8))) short short8;
typedef __attribute__((ext_vector_type(4))) float f32x4;

__device__ __forceinline__ float bflo(unsigned u) { return __uint_as_float(u << 16); }
__device__ __forceinline__ float bfhi(unsigned u) { return __uint_as_float(u & 0xffff0000u); }
__device__ __forceinline__ unsigned packbf(float a, float b) {  // lo=a, hi=b, RNE
  unsigned ua = __float_as_uint(a); ua = ua + 0x7fffu + ((ua >> 16) & 1);
  unsigned ub = __float_as_uint(b); ub = ub + 0x7fffu + ((ub >> 16) & 1);
  return (ua >> 16) | (ub & 0xffff0000u);
}
__device__ __forceinline__ unsigned short f2bf(float a) {
  unsigned ua = __float_as_uint(a); ua = ua + 0x7fffu + ((ua >> 16) & 1);
  return (unsigned short)(ua >> 16);
}

// ---------------------------------------------------------------- pass 1
__global__ __launch_bounds__(256) void k_gamma(const float* __restrict__ x,
                                               const float* __restrict__ W,
                                               const float* __restrict__ b,
                                               float* __restrict__ gt) {
  __shared__ float Wt[K][D];
  __shared__ float bl[K];
  int tid = threadIdx.x;
  for (int it = 0; it < 4; ++it) {
    int idx = it * 256 + tid;
    Wt[idx & 7][idx >> 3] = W[idx];
  }
  if (tid < K) bl[tid] = b[tid];
  __syncthreads();

  int s = blockIdx.x * 256 + tid;
  float li[K];
#pragma unroll
  for (int k = 0; k < K; ++k) li[k] = bl[k];
  const float4* xr = (const float4*)(x + (size_t)s * D);
#pragma unroll 8
  for (int i = 0; i < 32; ++i) {
    float4 xv = xr[i];
#pragma unroll
    for (int k = 0; k < K; ++k) {
      float4 wv = *(const float4*)&Wt[k][i * 4];
      li[k] += xv.x * wv.x + xv.y * wv.y + xv.z * wv.z + xv.w * wv.w;
    }
  }
  float m = li[0];
#pragma unroll
  for (int k = 1; k < K; ++k) m = fmaxf(m, li[k]);
  float p[K];
  float sum = 0.f;
#pragma unroll
  for (int k = 0; k < K; ++k) { p[k] = expf(li[k] - m); sum += p[k]; }
  float inv = 1.0f / sum;
  int ch = s >> 6, sl = s & 63;
#pragma unroll
  for (int k = 0; k < K; ++k) gt[(size_t)ch * (K * 64) + k * 64 + sl] = p[k] * inv;
}

// ---------------------------------------------------------------- pass 2
// bf16 copies of x: xb row-major, xt chunk-transposed [S/64][128 d][64 s]
__global__ __launch_bounds__(256) void k_xprep(const float* __restrict__ x,
                                               unsigned short* __restrict__ xb,
                                               unsigned short* __restrict__ xt) {
  __shared__ unsigned short xr[64 * 136];   // [64 s][128 d + 8 pad]
  int tid = threadIdx.x;
  for (int c = 0; c < 4; ++c) {
    int sb = blockIdx.x * 256 + c * 64;
    if (c) __syncthreads();
    {  // stage: thread covers sample s=tid>>2, d-block (tid&3)*32
      int s = tid >> 2, db = (tid & 3) * 32;
      const float4* src = (const float4*)(x + (size_t)(sb + s) * D + db);
#pragma unroll
      for (int j = 0; j < 4; ++j) {
        float4 v0 = src[j * 2], v1 = src[j * 2 + 1];
        unsigned u0 = packbf(v0.x, v0.y), u1 = packbf(v0.z, v0.w);
        unsigned u2 = packbf(v1.x, v1.y), u3 = packbf(v1.z, v1.w);
        uint4 o = {u0, u1, u2, u3};
        *(uint4*)&xr[s * 136 + db + j * 8] = o;
      }
    }
    __syncthreads();
    {  // xb write: thread f -> 64B row-major
      int s = tid >> 2, u0 = (tid & 3) * 4;
      uint4* dst = (uint4*)(xb + (size_t)(sb + s) * D) + u0;
#pragma unroll
      for (int j = 0; j < 4; ++j) dst[j] = *(const uint4*)&xr[s * 136 + (u0 + j) * 8];
    }
    {  // xt write: thread f -> 64B of [d][64 s]
      int d = tid >> 1, lu0 = (tid & 1) * 4;
      uint4* dst = (uint4*)(xt + (size_t)(sb >> 6) * (D * 64) + d * 64) + lu0;
#pragma unroll
      for (int j = 0; j < 4; ++j) {
        int s0 = (lu0 + j) * 8;
        unsigned w[4];
#pragma unroll
        for (int q = 0; q < 4; ++q) {
          unsigned lo = xr[(s0 + 2 * q) * 136 + d];
          unsigned hi = xr[(s0 + 2 * q + 1) * 136 + d];
          w[q] = lo | (hi << 16);
        }
        uint4 o = {w[0], w[1], w[2], w[3]};
        dst[j] = o;
      }
    }
  }
}

// ---------------------------------------------------------------- pass 3
// M2_k partial over 2048-sample chunk via MFMA; z = sqrt(g)*x staged in LDS.
__global__ __launch_bounds__(256) void k_m2(const unsigned short* __restrict__ xt,
                                            const float* __restrict__ gt,
                                            float* __restrict__ m2p,
                                            float* __restrict__ msp,
                                            float* __restrict__ nkp) {
  __shared__ unsigned short zt[D * 64];     // 16KB, unit-swizzled
  __shared__ float gbuf[2][64], sgbuf[2][64];
  __shared__ float msred[256];
  int tid = threadIdx.x;
  int cblk = blockIdx.x, k = blockIdx.y;
  int ch0 = cblk * 32;

  int w = tid >> 6;
  int m0 = (w >> 1) * 64, n0 = (w & 1) * 64;
  int lg = (tid >> 4) & 3, ll = tid & 15;

  const uint4* xtg = (const uint4*)xt;
  uint4 xr[4];
  {
    const uint4* src = xtg + (size_t)ch0 * 1024 + tid * 4;
#pragma unroll
    for (int j = 0; j < 4; ++j) xr[j] = src[j];
  }
  float gacc = 0.f, gn = 0.f;
  if (tid < 64) {
    float g0 = gt[(size_t)ch0 * (K * 64) + k * 64 + tid];
    gbuf[0][tid] = g0; sgbuf[0][tid] = sqrtf(g0); gacc = g0;
    gn = gt[(size_t)(ch0 + 1) * (K * 64) + k * 64 + tid];
  }
  __syncthreads();

  f32x4 acc[4][4];
#pragma unroll
  for (int mi = 0; mi < 4; ++mi)
#pragma unroll
    for (int ni = 0; ni < 4; ++ni) acc[mi][ni] = (f32x4)0.f;

  float msa = 0.f;
  int dloc = tid >> 1;

  for (int t = 0; t < 32; ++t) {
    int cur = t & 1;
    // ---- z staging (uses xr regs + gbuf[cur])
#pragma unroll
    for (int j = 0; j < 4; ++j) {
      int lu = (tid & 1) * 4 + j, s0 = lu * 8;
      uint4 q = xr[j];
      float x0 = bflo(q.x), x1 = bfhi(q.x), x2 = bflo(q.y), x3 = bfhi(q.y);
      float x4 = bflo(q.z), x5 = bfhi(q.z), x6 = bflo(q.w), x7 = bfhi(q.w);
      float4 g0 = *(const float4*)&gbuf[cur][s0];
      float4 g1 = *(const float4*)&gbuf[cur][s0 + 4];
      float4 s0v = *(const float4*)&sgbuf[cur][s0];
      float4 s1v = *(const float4*)&sgbuf[cur][s0 + 4];
      msa += x0 * g0.x + x1 * g0.y + x2 * g0.z + x3 * g0.w +
             x4 * g1.x + x5 * g1.y + x6 * g1.z + x7 * g1.w;
      unsigned u0 = packbf(x0 * s0v.x, x1 * s0v.y);
      unsigned u1 = packbf(x2 * s0v.z, x3 * s0v.w);
      unsigned u2 = packbf(x4 * s1v.x, x5 * s1v.y);
      unsigned u3 = packbf(x6 * s1v.z, x7 * s1v.w);
      uint4 o = {u0, u1, u2, u3};
      *(uint4*)&zt[dloc * 64 + (lu ^ (dloc & 7)) * 8] = o;
    }
    // ---- gamma pipeline + prefetch next chunk
    if (tid < 64 && t + 1 < 32) {
      gbuf[cur ^ 1][tid] = gn; sgbuf[cur ^ 1][tid] = sqrtf(gn); gacc += gn;
    }
    if (t + 1 < 32) {
      const uint4* src = xtg + (size_t)(ch0 + t + 1) * 1024 + tid * 4;
#pragma unroll
      for (int j = 0; j < 4; ++j) xr[j] = src[j];
      if (tid < 64 && t + 2 < 32)
        gn = gt[(size_t)(ch0 + t + 2) * (K * 64) + k * 64 + tid];
    }
    __syncthreads();   // zt staged
    // ---- MFMA
#pragma unroll
    for (int ksub = 0; ksub < 2; ++ksub) {
      short8 af[4], bf_[4];
#pragma unroll
      for (int mi = 0; mi < 4; ++mi) {
        int dd = m0 + mi * 16 + ll;
        int ua = ksub * 4 + lg;
        af[mi] = *(const short8*)&zt[dd * 64 + (ua ^ (dd & 7)) * 8];
      }
#pragma unroll
      for (int ni = 0; ni < 4; ++ni) {
        int ee = n0 + ni * 16 + ll;
        int ub = ksub * 4 + lg;
        bf_[ni] = *(const short8*)&zt[ee * 64 + (ub ^ (ee & 7)) * 8];
      }
#pragma unroll
      for (int mi = 0; mi < 4; ++mi)
#pragma unroll
        for (int ni = 0; ni < 4; ++ni)
          acc[mi][ni] = __builtin_amdgcn_mfma_f32_16x16x32_bf16(
              af[mi], bf_[ni], acc[mi][ni], 0, 0, 0);
    }
    __syncthreads();   // MFMA done -> zt free
  }

  // ---- outputs
  size_t base = (size_t)(k * NCH + cblk) << 14;
#pragma unroll
  for (int mi = 0; mi < 4; ++mi)
#pragma unroll
    for (int ni = 0; ni < 4; ++ni)
#pragma unroll
      for (int r = 0; r < 4; ++r) {
        int row = m0 + mi * 16 + lg * 4 + r;
        int col = n0 + ni * 16 + ll;
        m2p[base + row * D + col] = acc[mi][ni][r];
      }
  msred[tid] = msa;
  __syncthreads();
  if (tid < 128) msp[(size_t)(k * NCH + cblk) * D + tid] = msred[2 * tid] + msred[2 * tid + 1];
  if (tid < 64) {
    float v = gacc;
#pragma unroll
    for (int off = 1; off < 64; off <<= 1) v += __shfl_xor(v, off);
    if (tid == 0) nkp[k * NCH + cblk] = v;
  }
}

// ---------------------------------------------------------------- pass 4a
__global__ __launch_bounds__(256) void k_redmu(const float* __restrict__ msp,
                                               const float* __restrict__ nkp,
                                               float* __restrict__ Nk,
                                               float* __restrict__ mu) {
  __shared__ float sNk[K];
  int tid = threadIdx.x;
  if (tid < K) {
    float s = 0.f;
    for (int c = 0; c < NCH; ++c) s += nkp[tid * NCH + c];
    sNk[tid] = s;
    Nk[tid] = s;
  }
  __syncthreads();
  for (int it = 0; it < (K * D) / 256; ++it) {
    int idx = it * 256 + tid;
    int k = idx >> 7;
    float s = 0.f;
    for (int c = 0; c < NCH; ++c) s += msp[(size_t)(k * NCH + c) * D + (idx & 127)];
    mu[idx] = s / sNk[k];
  }
}

// ---------------------------------------------------------------- pass 4b
__global__ __launch_bounds__(256) void k_sigma(const float* __restrict__ m2p,
                                               const float* __restrict__ Nk,
                                               const float* __restrict__ mu,
                                               float* __restrict__ sigma) {
  int tid = threadIdx.x;
  int k = blockIdx.y;
  int flat = blockIdx.x * 256 + tid;
  int d = flat >> 7, e = flat & 127;
  float s = 0.f;
  for (int c = 0; c < NCH; ++c) s += m2p[((size_t)(k * NCH + c) << 14) + flat];
  sigma[((size_t)k << 14) + flat] = s / Nk[k] - mu[k * D + d] * mu[k * D + e];
}

// ---------------------------------------------------------------- pass 5
// Blocked symmetric sweep -> Sigma^{-1} (bf16 out), v = Sigma^{-1} mu, c2 = mu.v
#define PBW 36
#define YTW 132
#define AROT(r, c) (((r) << 7) + ((((c) + (((r) >> 3) << 2))) & 127))

__global__ __launch_bounds__(256) void k_inv(const float* __restrict__ sigma,
                                             const float* __restrict__ Nk,
                                             const float* __restrict__ mu,
                                             unsigned short* __restrict__ Bh,
                                             float* __restrict__ vv,
                                             float* __restrict__ coef,
                                             float* __restrict__ c2) {
  __shared__ float A[D * D];
  __shared__ float Pb[32 * PBW];
  __shared__ float Cb[32 * 128];
  __shared__ float Yt[32 * YTW];
  __shared__ float Rb[32 * 128];
  __shared__ float mus[D];
  int tid = threadIdx.x;
  int k = blockIdx.x;
  const float* sg = sigma + ((size_t)k << 14);

#pragma unroll
  for (int i = 0; i < 16; ++i) {
    int f = tid + 256 * i;
    int r = f >> 5, c4 = (f & 31) << 2;
    *(float4*)&A[AROT(r, c4)] = *(const float4*)&sg[((size_t)f) << 2];
  }
  if (tid < D) mus[tid] = mu[k * D + tid];
  __syncthreads();

  float ldet = 0.f;
  int mr = tid >> 3, mq = tid & 7;
  int ci = tid >> 1, ch = tid & 1;
  int w = tid >> 6, l = tid & 63;
  int d0 = (((w >> 1) << 3) + (l >> 3)) * 8;
  int e0 = (((w & 1) << 3) + (l & 7)) * 8;

  for (int t = 0; t < 4; ++t) {
    int tb = t * 32;
    *(float4*)&Pb[mr * PBW + 4 * mq] = *(const float4*)&A[AROT(tb + mr, tb + 4 * mq)];
#pragma unroll
    for (int q = 0; q < 4; ++q) {
      int f = tid + 256 * q;
      int rr = f >> 5, cc4 = (f & 31) << 2;
      *(float4*)&Rb[rr * 128 + cc4] = *(const float4*)&A[AROT(tb + rr, cc4)];
    }
#pragma unroll
    for (int n4 = 0; n4 < 4; ++n4) {
      float4 q4 = *(const float4*)&A[AROT(ci, tb + 16 * ch + 4 * n4)];
      int nb = 16 * ch + 4 * n4;
      Cb[(nb + 0) * 128 + ci] = q4.x;
      Cb[(nb + 1) * 128 + ci] = q4.y;
      Cb[(nb + 2) * 128 + ci] = q4.z;
      Cb[(nb + 3) * 128 + ci] = q4.w;
    }
    __syncthreads();

    for (int c = 0; c < 32; ++c) {
      float dpv = Pb[c * PBW + c];
      float piv = 1.0f / dpv;
      ldet += logf(dpv);
      float4 rq = *(const float4*)&Pb[c * PBW + 4 * mq];
      float cv = Pb[mr * PBW + c];
      __syncthreads();
      float4 rfac = {piv * rq.x, piv * rq.y, piv * rq.z, piv * rq.w};
      float4 own = *(const float4*)&Pb[mr * PBW + 4 * mq];
      bool pr = (mr == c);
      float4 up;
      up.x = pr ? rfac.x : own.x - cv * rfac.x;
      up.y = pr ? rfac.y : own.y - cv * rfac.y;
      up.z = pr ? rfac.z : own.z - cv * rfac.z;
      up.w = pr ? rfac.w : own.w - cv * rfac.w;
      int cq = c >> 2, cl = c & 3;
      if (mq == cq) {
        float nv = pr ? -piv : cv * piv;
        if (cl == 0) up.x = nv;
        else if (cl == 1) up.y = nv;
        else if (cl == 2) up.z = nv;
        else up.w = nv;
      }
      *(float4*)&Pb[mr * PBW + 4 * mq] = up;
      __syncthreads();
    }

    {
      int rs = tid >> 3, cs = tid & 7;
      float accY[4][4] = {};
#pragma unroll 8
      for (int n = 0; n < 32; ++n) {
        float4 cq4 = *(const float4*)&Cb[n * 128 + 4 * rs];
        float4 pq = *(const float4*)&Pb[n * PBW + 4 * cs];
        float ca[4] = {cq4.x, cq4.y, cq4.z, cq4.w};
        float pa[4] = {pq.x, pq.y, pq.z, pq.w};
#pragma unroll
        for (int q = 0; q < 4; ++q)
#pragma unroll
          for (int j = 0; j < 4; ++j) accY[q][j] -= ca[q] * pa[j];
      }
#pragma unroll
      for (int j = 0; j < 4; ++j) {
        float4 o = {accY[0][j], accY[1][j], accY[2][j], accY[3][j]};
        *(float4*)&Yt[(4 * cs + j) * YTW + 4 * rs] = o;
      }
    }
    __syncthreads();

    {
      float acc[8][8];
#pragma unroll
      for (int di = 0; di < 8; ++di)
#pragma unroll
        for (int e4 = 0; e4 < 2; ++e4) {
          float4 a = *(const float4*)&A[AROT(d0 + di, e0 + 4 * e4)];
          acc[di][e4 * 4 + 0] = a.x; acc[di][e4 * 4 + 1] = a.y;
          acc[di][e4 * 4 + 2] = a.z; acc[di][e4 * 4 + 3] = a.w;
        }
#pragma unroll 4
      for (int m = 0; m < 32; ++m) {
        float4 ya = *(const float4*)&Yt[m * YTW + d0];
        float4 yb = *(const float4*)&Yt[m * YTW + d0 + 4];
        float4 ra = *(const float4*)&Rb[m * 128 + e0];
        float4 rb2 = *(const float4*)&Rb[m * 128 + e0 + 4];
        float av[8] = {ya.x, ya.y, ya.z, ya.w, yb.x, yb.y, yb.z, yb.w};
        float bv[8] = {ra.x, ra.y, ra.z, ra.w, rb2.x, rb2.y, rb2.z, rb2.w};
#pragma unroll
        for (int di = 0; di < 8; ++di)
#pragma unroll
          for (int ei = 0; ei < 8; ++ei) acc[di][ei] -= av[di] * bv[ei];
      }
#pragma unroll
      for (int di = 0; di < 8; ++di)
#pragma unroll
        for (int e4 = 0; e4 < 2; ++e4) {
          float4 o = {acc[di][e4 * 4 + 0], acc[di][e4 * 4 + 1],
                      acc[di][e4 * 4 + 2], acc[di][e4 * 4 + 3]};
          *(float4*)&A[AROT(d0 + di, e0 + 4 * e4)] = o;
        }
    }
    __syncthreads();

#pragma unroll
    for (int qq = 0; qq < 4; ++qq) {
      int j0 = 4 * mq + 32 * qq;
      *(float4*)&A[AROT(tb + mr, j0)] = *(const float4*)&Yt[mr * YTW + j0];
    }
    if (ci < tb || ci >= tb + 32) {
#pragma unroll
      for (int n = 0; n < 16; ++n) {
        int mloc = 16 * ch + ((n + ci) & 15);
        A[AROT(ci, tb + mloc)] = Yt[mloc * YTW + ci];
      }
    }
    __syncthreads();
    *(float4*)&A[AROT(tb + mr, tb + 4 * mq)] = *(const float4*)&Pb[mr * PBW + 4 * mq];
    __syncthreads();
  }

  // ---- outputs: Bh = bf16(-A), v = -A mu, c2 = mu.v, coef
#pragma unroll
  for (int i = 0; i < 16; ++i) {
    int f = tid + 256 * i;
    int r = f >> 5, c4 = (f & 31) << 2;
    float4 a = *(const float4*)&A[AROT(r, c4)];
    unsigned u0 = packbf(-a.x, -a.y), u1 = packbf(-a.z, -a.w);
    uint2 o = {u0, u1};
    *(uint2*)(Bh + (size_t)k * (D * D) + f * 4) = o;
  }
  float c2part = 0.f;
  if (tid < D) {
    float s = 0.f;
#pragma unroll 8
    for (int q = 0; q < 32; ++q) {
      float4 a = *(const float4*)&A[AROT(tid, q << 2)];
      float4 m = *(const float4*)&mus[q << 2];
      s += a.x * m.x + a.y * m.y + a.z * m.z + a.w * m.w;
    }
    vv[k * D + tid] = -s;
    c2part = mus[tid] * (-s);
  }
  __syncthreads();
  {
    float v = c2part;
#pragma unroll
    for (int off = 1; off < 64; off <<= 1) v += __shfl_xor(v, off);
    if ((tid & 63) == 0) Pb[tid >> 6] = v;   // reuse Pb as scratch
  }
  __syncthreads();
  if (tid == 0) {
    c2[k] = Pb[0] + Pb[1];
    coef[k] = logf(Nk[k] * (1.0f / (float)S_LEN)) -
              0.5f * ((float)D * LOG_2PI + ldet);
  }
}

// ---------------------------------------------------------------- pass 6
// y = x Sigma^{-1} via MFMA (B symmetric); maha = sum x*(y-2v) + c2; online LSE.
__global__ __launch_bounds__(256) void k_maha(const unsigned short* __restrict__ xb,
                                              const unsigned short* __restrict__ Bh,
                                              const float* __restrict__ vv,
                                              const float* __restrict__ coef,
                                              const float* __restrict__ c2,
                                              float* __restrict__ epart) {
  __shared__ unsigned short xbt[MB_S * D];  // 32KB, unit-swizzled [s][u^(s&7)]
  __shared__ unsigned short Bt[D * 64];     // 16KB, [e][u^(e&7)]
  __shared__ float vls[K * D];
  __shared__ float cfl[K], c2l[K];
  __shared__ float wsum[4];
  int tid = threadIdx.x;
  int bs = blockIdx.x * MB_S;
  int w = tid >> 6;
  int m0 = w * 32;
  int lg = (tid >> 4) & 3, ll = tid & 15;

  // ---- stage x tile (swizzled)
  {
    int s = tid >> 1, u0 = (tid & 1) * 8;
    const uint4* src = (const uint4*)(xb + (size_t)(bs + s) * D) + u0;
#pragma unroll
    for (int j = 0; j < 8; ++j)
      *(uint4*)&xbt[s * D + ((u0 + j) ^ (s & 7)) * 8] = src[j];
  }
#pragma unroll
  for (int i = 0; i < 4; ++i) { int idx = i * 256 + tid; vls[idx] = vv[idx]; }
  if (tid < K) { cfl[tid] = coef[tid]; c2l[tid] = c2[tid]; }

  // ---- B prologue (regs)
  const uint4* bg = (const uint4*)Bh;
  uint4 br[4];
  {
    int e = tid >> 1, u0b = (tid & 1) * 4;
    const uint4* src = bg + (size_t)0 * 2048 + e * 16 + 0 * 8 + u0b;
#pragma unroll
    for (int j = 0; j < 4; ++j) br[j] = src[j];
  }

  f32x4 acc[2][8];
  float mrun[2][4], srun[2][4];
#pragma unroll
  for (int mi = 0; mi < 2; ++mi)
#pragma unroll
    for (int r = 0; r < 4; ++r) { mrun[mi][r] = -1e30f; srun[mi][r] = 0.f; }

  for (int it = 0; it < 16; ++it) {
    int k = it >> 1, dh = it & 1;
    // ---- write B tile from regs (swizzled)
    {
      int e = tid >> 1, lu0 = (tid & 1) * 4;
#pragma unroll
      for (int j = 0; j < 4; ++j)
        *(uint4*)&Bt[e * 64 + ((lu0 + j) ^ (e & 7)) * 8] = br[j];
    }
    // ---- issue next B loads
    if (it < 15) {
      int kn = (it + 1) >> 1, dhn = (it + 1) & 1;
      int e = tid >> 1, u0b = (tid & 1) * 4;
      const uint4* src = bg + (size_t)kn * 2048 + e * 16 + dhn * 8 + u0b;
#pragma unroll
      for (int j = 0; j < 4; ++j) br[j] = src[j];
    }
    if (dh == 0) {
#pragma unroll
      for (int mi = 0; mi < 2; ++mi)
#pragma unroll
        for (int ni = 0; ni < 8; ++ni) acc[mi][ni] = (f32x4)0.f;
    }
    __syncthreads();   // Bt staged (and xbt/vls on it==0)
    // ---- MFMA
#pragma unroll
    for (int ksub = 0; ksub < 2; ++ksub) {
      short8 af[2];
#pragma unroll
      for (int mi = 0; mi < 2; ++mi) {
        int srow = m0 + mi * 16 + ll;
        int ua = dh * 8 + ksub * 4 + lg;
        af[mi] = *(const short8*)&xbt[srow * D + (ua ^ (srow & 7)) * 8];
      }
#pragma unroll
      for (int ni = 0; ni < 8; ++ni) {
        int e = ni * 16 + ll;
        int ub = ksub * 4 + lg;
        short8 bfr = *(const short8*)&Bt[e * 64 + (ub ^ (e & 7)) * 8];
#pragma unroll
        for (int mi = 0; mi < 2; ++mi)
          acc[mi][ni] = __builtin_amdgcn_mfma_f32_16x16x32_bf16(
              af[mi], bfr, acc[mi][ni], 0, 0, 0);
      }
    }
    // ---- epilogue at k boundary
    if (dh == 1) {
      float part[2][4] = {};
#pragma unroll
      for (int ni = 0; ni < 8; ++ni) {
        int col = ni * 16 + ll;
        float w2 = -2.0f * vls[k * D + col];
#pragma unroll
        for (int mi = 0; mi < 2; ++mi)
#pragma unroll
          for (int r = 0; r < 4; ++r) {
            int srow = m0 + mi * 16 + lg * 4 + r;
            unsigned xv = xbt[srow * D + ((col >> 3) ^ (srow & 7)) * 8 + (col & 7)];
            part[mi][r] += bflo(xv) * (acc[mi][ni][r] + w2);
          }
      }
#pragma unroll
      for (int mi = 0; mi < 2; ++mi)
#pragma unroll
        for (int r = 0; r < 4; ++r) {
          float p = part[mi][r];
          p += __shfl_xor(p, 1); p += __shfl_xor(p, 2);
          p += __shfl_xor(p, 4); p += __shfl_xor(p, 8);
          float a = cfl[k] - 0.5f * (p + c2l[k]);
          if (a > mrun[mi][r]) {
            srun[mi][r] = srun[mi][r] * expf(mrun[mi][r] - a) + 1.0f;
            mrun[mi][r] = a;
          } else {
            srun[mi][r] += expf(a - mrun[mi][r]);
          }
        }
    }
    __syncthreads();   // MFMA/epilogue done -> Bt free
  }

  // ---- block reduction of log-densities
  float v = 0.f;
#pragma unroll
  for (int mi = 0; mi < 2; ++mi)
#pragma unroll
    for (int r = 0; r < 4; ++r) v += mrun[mi][r] + logf(srun[mi][r]);
  v += __shfl_xor(v, 16);
  v += __shfl_xor(v, 32);
  if ((tid & 63) == 0) wsum[w] = v;
  __syncthreads();
  if (tid == 0) epart[blockIdx.x] = wsum[0] + wsum[1] + wsum[2] + wsum[3];
}

// ---------------------------------------------------------------- pass 7
__global__ __launch_bounds__(256) void k_final(const float* __restrict__ epart,
                                               float* __restrict__ out) {
  __shared__ double sw[4];
  int tid = threadIdx.x;
  double a = (double)epart[tid] + (double)epart[tid + 256];
#pragma unroll
  for (int off = 1; off < 64; off <<= 1) a += __shfl_xor(a, off);
  if ((tid & 63) == 0) sw[tid >> 6] = a;
  __syncthreads();
  if (tid == 0) out[0] = (float)(-(sw[0] + sw[1] + sw[2] + sw[3]));
}

// ----------------------------------------------------------------
extern "C" void kernel_launch(void* const* d_in, const int* in_sizes, int n_in,
                              void* d_out, int out_size, void* d_ws, size_t ws_size,
                              hipStream_t stream) {
  (void)in_sizes; (void)n_in; (void)out_size; (void)ws_size;
  const float* x = (const float*)d_in[0];
  const float* W = (const float*)d_in[1];
  const float* b = (const float*)d_in[2];
  float* out = (float*)d_out;
  float* ws = (float*)d_ws;

  float* gtp   = ws + OFF_GT;
  float* m2p   = ws + OFF_M2P;
  float* msp   = ws + OFF_MSP;
  float* nkp   = ws + OFF_NKP;
  float* Nk    = ws + OFF_NK;
  float* mu    = ws + OFF_MU;
  float* sigma = ws + OFF_SIGMA;
  float* wvp   = ws + OFF_WV;
  float* coefp = ws + OFF_COEF;
  float* c2p   = ws + OFF_C2;
  float* epart = ws + OFF_EPART;
  unsigned short* xb = (unsigned short*)(ws + OFF_XB);
  unsigned short* xt = (unsigned short*)(ws + OFF_XT);
  unsigned short* Bh = (unsigned short*)(ws + OFF_BH);

  k_gamma<<<S_LEN / 256, 256, 0, stream>>>(x, W, b, gtp);
  k_xprep<<<S_LEN / 256, 256, 0, stream>>>(x, xb, xt);
  k_m2<<<dim3(NCH, K), 256, 0, stream>>>(xt, gtp, m2p, msp, nkp);
  k_redmu<<<1, 256, 0, stream>>>(msp, nkp, Nk, mu);
  k_sigma<<<dim3(64, K), 256, 0, stream>>>(m2p, Nk, mu, sigma);
  k_inv<<<K, 256, 0, stream>>>(sigma, Nk, mu, Bh, wvp, coefp, c2p);
  k_maha<<<NMB, 256, 0, stream>>>(xb, Bh, wvp, coefp, c2p, epart);
  k_final<<<1, 256, 0, stream>>>(epart, out);
}

// Round 7
// 298.743 us; speedup vs baseline: 4.7077x; 1.1289x over previous
//
#include <hip/hip_runtime.h>

// GaussianMixture energy on MI355X — round 7: k_maha restructured to pure
// dataflow (A-frags + epilogue-x in registers, full-B_k LDS phases).
// S=65536, D=128, K=8.
//
// Pipeline:
//  1. k_gamma : gamma = softmax(x@W + b) -> gamma-transposed gt[S/64][8][64]
//  2. k_xprep : bf16 copies of x: xb[S][128] row-major, xt[S/64][128][64] chunk-transposed
//  3. k_m2    : M2_k = (sqrt(g) x)^T (sqrt(g) x) via mfma_f32_16x16x32_bf16; msp, nkp
//  4. k_redmu : Nk, mu
//  5. k_sigma : sigma_k = M2_k/Nk - mu mu^T   (fp32)
//  6. k_inv   : blocked symmetric sweep -> Sigma^{-1} (bf16 out), v=Sigma^{-1}mu,
//               c2=mu.v, coef
//  7. k_maha  : y = x Sigma^{-1} via MFMA (B symmetric -> no transpose);
//               maha = sum x*(y-2v)+c2; online LSE over k
//  8. k_final : energy = -sum
//
// Round 6->7 (k_maha only): x A-fragments and epilogue-x values are k-invariant
// -> loaded ONCE into registers from global (no x LDS tile, no per-k scalar LDS
// reads). Full 32KB B_k staged per phase (64 MFMA between barriers, was 32),
// next-k B prefetched into regs during MFMA. LDS unit-swizzle du^=(e&7) makes
// every b128 access bank-uniform (8/bank = minimum). Branchless online LSE.

#define S_LEN 65536
#define D 128
#define K 8
#define NCH 32                    // k_m2 S-chunks (2048 samples each)
#define KSTEP 64                  // samples per xt chunk / MFMA K-tile pair
#define NXTCH (S_LEN / KSTEP)     // 1024
#define MB_S 128                  // k_maha samples per block
#define NMB (S_LEN / MB_S)        // 512

// workspace layout (float offsets)
#define OFF_GT 0
#define SZ_GT (NXTCH * K * KSTEP)            // 524288
#define OFF_M2P (OFF_GT + SZ_GT)
#define SZ_M2P (K * NCH * D * D)             // 4194304
#define OFF_MSP (OFF_M2P + SZ_M2P)
#define SZ_MSP (K * NCH * D)                 // 32768
#define OFF_NKP (OFF_MSP + SZ_MSP)
#define SZ_NKP (K * NCH)                     // 256
#define OFF_NK (OFF_NKP + SZ_NKP)
#define OFF_MU (OFF_NK + 8)
#define OFF_SIGMA (OFF_MU + K * D)
#define OFF_WV (OFF_SIGMA + K * D * D)
#define OFF_COEF (OFF_WV + K * D)
#define OFF_C2 (OFF_COEF + 8)
#define OFF_EPART (OFF_C2 + 8)
#define OFF_XB (OFF_EPART + NMB)             // bf16: S*128 shorts = 4194304 floats
#define SZ_XB (S_LEN * D / 2)
#define OFF_XT (OFF_XB + SZ_XB)
#define SZ_XT (S_LEN * D / 2)
#define OFF_BH (OFF_XT + SZ_XT)              // bf16 Sigma^{-1}: 65536 floats
// total ~13.3M floats (~53 MB)

#define LOG_2PI 1.8378770664093453f

typedef __attribute__((ext_vector_type(8))) short short8;
typedef __attribute__((ext_vector_type(4))) float f32x4;

__device__ __forceinline__ float bflo(unsigned u) { return __uint_as_float(u << 16); }
__device__ __forceinline__ float bfhi(unsigned u) { return __uint_as_float(u & 0xffff0000u); }
__device__ __forceinline__ float bfu(unsigned short u) { return __uint_as_float((unsigned)u << 16); }
__device__ __forceinline__ unsigned packbf(float a, float b) {  // lo=a, hi=b, RNE
  unsigned ua = __float_as_uint(a); ua = ua + 0x7fffu + ((ua >> 16) & 1);
  unsigned ub = __float_as_uint(b); ub = ub + 0x7fffu + ((ub >> 16) & 1);
  return (ua >> 16) | (ub & 0xffff0000u);
}

// ---------------------------------------------------------------- pass 1
__global__ __launch_bounds__(256) void k_gamma(const float* __restrict__ x,
                                               const float* __restrict__ W,
                                               const float* __restrict__ b,
                                               float* __restrict__ gt) {
  __shared__ float Wt[K][D];
  __shared__ float bl[K];
  int tid = threadIdx.x;
  for (int it = 0; it < 4; ++it) {
    int idx = it * 256 + tid;
    Wt[idx & 7][idx >> 3] = W[idx];
  }
  if (tid < K) bl[tid] = b[tid];
  __syncthreads();

  int s = blockIdx.x * 256 + tid;
  float li[K];
#pragma unroll
  for (int k = 0; k < K; ++k) li[k] = bl[k];
  const float4* xr = (const float4*)(x + (size_t)s * D);
#pragma unroll 8
  for (int i = 0; i < 32; ++i) {
    float4 xv = xr[i];
#pragma unroll
    for (int k = 0; k < K; ++k) {
      float4 wv = *(const float4*)&Wt[k][i * 4];
      li[k] += xv.x * wv.x + xv.y * wv.y + xv.z * wv.z + xv.w * wv.w;
    }
  }
  float m = li[0];
#pragma unroll
  for (int k = 1; k < K; ++k) m = fmaxf(m, li[k]);
  float p[K];
  float sum = 0.f;
#pragma unroll
  for (int k = 0; k < K; ++k) { p[k] = expf(li[k] - m); sum += p[k]; }
  float inv = 1.0f / sum;
  int ch = s >> 6, sl = s & 63;
#pragma unroll
  for (int k = 0; k < K; ++k) gt[(size_t)ch * (K * 64) + k * 64 + sl] = p[k] * inv;
}

// ---------------------------------------------------------------- pass 2
// bf16 copies of x: xb row-major, xt chunk-transposed [S/64][128 d][64 s]
__global__ __launch_bounds__(256) void k_xprep(const float* __restrict__ x,
                                               unsigned short* __restrict__ xb,
                                               unsigned short* __restrict__ xt) {
  __shared__ unsigned short xr[64 * 136];   // [64 s][128 d + 8 pad]
  int tid = threadIdx.x;
  for (int c = 0; c < 4; ++c) {
    int sb = blockIdx.x * 256 + c * 64;
    if (c) __syncthreads();
    {  // stage: thread covers sample s=tid>>2, d-block (tid&3)*32
      int s = tid >> 2, db = (tid & 3) * 32;
      const float4* src = (const float4*)(x + (size_t)(sb + s) * D + db);
#pragma unroll
      for (int j = 0; j < 4; ++j) {
        float4 v0 = src[j * 2], v1 = src[j * 2 + 1];
        unsigned u0 = packbf(v0.x, v0.y), u1 = packbf(v0.z, v0.w);
        unsigned u2 = packbf(v1.x, v1.y), u3 = packbf(v1.z, v1.w);
        uint4 o = {u0, u1, u2, u3};
        *(uint4*)&xr[s * 136 + db + j * 8] = o;
      }
    }
    __syncthreads();
    {  // xb write: thread f -> 64B row-major
      int s = tid >> 2, u0 = (tid & 3) * 4;
      uint4* dst = (uint4*)(xb + (size_t)(sb + s) * D) + u0;
#pragma unroll
      for (int j = 0; j < 4; ++j) dst[j] = *(const uint4*)&xr[s * 136 + (u0 + j) * 8];
    }
    {  // xt write: thread f -> 64B of [d][64 s]
      int d = tid >> 1, lu0 = (tid & 1) * 4;
      uint4* dst = (uint4*)(xt + (size_t)(sb >> 6) * (D * 64) + d * 64) + lu0;
#pragma unroll
      for (int j = 0; j < 4; ++j) {
        int s0 = (lu0 + j) * 8;
        unsigned w[4];
#pragma unroll
        for (int q = 0; q < 4; ++q) {
          unsigned lo = xr[(s0 + 2 * q) * 136 + d];
          unsigned hi = xr[(s0 + 2 * q + 1) * 136 + d];
          w[q] = lo | (hi << 16);
        }
        uint4 o = {w[0], w[1], w[2], w[3]};
        dst[j] = o;
      }
    }
  }
}

// ---------------------------------------------------------------- pass 3
// M2_k partial over 2048-sample chunk via MFMA; z = sqrt(g)*x staged in LDS.
__global__ __launch_bounds__(256) void k_m2(const unsigned short* __restrict__ xt,
                                            const float* __restrict__ gt,
                                            float* __restrict__ m2p,
                                            float* __restrict__ msp,
                                            float* __restrict__ nkp) {
  __shared__ unsigned short zt[D * 64];     // 16KB, unit-swizzled
  __shared__ float gbuf[2][64], sgbuf[2][64];
  __shared__ float msred[256];
  int tid = threadIdx.x;
  int cblk = blockIdx.x, k = blockIdx.y;
  int ch0 = cblk * 32;

  int w = tid >> 6;
  int m0 = (w >> 1) * 64, n0 = (w & 1) * 64;
  int lg = (tid >> 4) & 3, ll = tid & 15;

  const uint4* xtg = (const uint4*)xt;
  uint4 xr[4];
  {
    const uint4* src = xtg + (size_t)ch0 * 1024 + tid * 4;
#pragma unroll
    for (int j = 0; j < 4; ++j) xr[j] = src[j];
  }
  float gacc = 0.f, gn = 0.f;
  if (tid < 64) {
    float g0 = gt[(size_t)ch0 * (K * 64) + k * 64 + tid];
    gbuf[0][tid] = g0; sgbuf[0][tid] = sqrtf(g0); gacc = g0;
    gn = gt[(size_t)(ch0 + 1) * (K * 64) + k * 64 + tid];
  }
  __syncthreads();

  f32x4 acc[4][4];
#pragma unroll
  for (int mi = 0; mi < 4; ++mi)
#pragma unroll
    for (int ni = 0; ni < 4; ++ni) acc[mi][ni] = (f32x4)0.f;

  float msa = 0.f;
  int dloc = tid >> 1;

  for (int t = 0; t < 32; ++t) {
    int cur = t & 1;
    // ---- z staging (uses xr regs + gbuf[cur])
#pragma unroll
    for (int j = 0; j < 4; ++j) {
      int lu = (tid & 1) * 4 + j, s0 = lu * 8;
      uint4 q = xr[j];
      float x0 = bflo(q.x), x1 = bfhi(q.x), x2 = bflo(q.y), x3 = bfhi(q.y);
      float x4 = bflo(q.z), x5 = bfhi(q.z), x6 = bflo(q.w), x7 = bfhi(q.w);
      float4 g0 = *(const float4*)&gbuf[cur][s0];
      float4 g1 = *(const float4*)&gbuf[cur][s0 + 4];
      float4 s0v = *(const float4*)&sgbuf[cur][s0];
      float4 s1v = *(const float4*)&sgbuf[cur][s0 + 4];
      msa += x0 * g0.x + x1 * g0.y + x2 * g0.z + x3 * g0.w +
             x4 * g1.x + x5 * g1.y + x6 * g1.z + x7 * g1.w;
      unsigned u0 = packbf(x0 * s0v.x, x1 * s0v.y);
      unsigned u1 = packbf(x2 * s0v.z, x3 * s0v.w);
      unsigned u2 = packbf(x4 * s1v.x, x5 * s1v.y);
      unsigned u3 = packbf(x6 * s1v.z, x7 * s1v.w);
      uint4 o = {u0, u1, u2, u3};
      *(uint4*)&zt[dloc * 64 + (lu ^ (dloc & 7)) * 8] = o;
    }
    // ---- gamma pipeline + prefetch next chunk
    if (tid < 64 && t + 1 < 32) {
      gbuf[cur ^ 1][tid] = gn; sgbuf[cur ^ 1][tid] = sqrtf(gn); gacc += gn;
    }
    if (t + 1 < 32) {
      const uint4* src = xtg + (size_t)(ch0 + t + 1) * 1024 + tid * 4;
#pragma unroll
      for (int j = 0; j < 4; ++j) xr[j] = src[j];
      if (tid < 64 && t + 2 < 32)
        gn = gt[(size_t)(ch0 + t + 2) * (K * 64) + k * 64 + tid];
    }
    __syncthreads();   // zt staged
    // ---- MFMA
#pragma unroll
    for (int ksub = 0; ksub < 2; ++ksub) {
      short8 af[4], bf_[4];
#pragma unroll
      for (int mi = 0; mi < 4; ++mi) {
        int dd = m0 + mi * 16 + ll;
        int ua = ksub * 4 + lg;
        af[mi] = *(const short8*)&zt[dd * 64 + (ua ^ (dd & 7)) * 8];
      }
#pragma unroll
      for (int ni = 0; ni < 4; ++ni) {
        int ee = n0 + ni * 16 + ll;
        int ub = ksub * 4 + lg;
        bf_[ni] = *(const short8*)&zt[ee * 64 + (ub ^ (ee & 7)) * 8];
      }
#pragma unroll
      for (int mi = 0; mi < 4; ++mi)
#pragma unroll
        for (int ni = 0; ni < 4; ++ni)
          acc[mi][ni] = __builtin_amdgcn_mfma_f32_16x16x32_bf16(
              af[mi], bf_[ni], acc[mi][ni], 0, 0, 0);
    }
    __syncthreads();   // MFMA done -> zt free
  }

  // ---- outputs
  size_t base = (size_t)(k * NCH + cblk) << 14;
#pragma unroll
  for (int mi = 0; mi < 4; ++mi)
#pragma unroll
    for (int ni = 0; ni < 4; ++ni)
#pragma unroll
      for (int r = 0; r < 4; ++r) {
        int row = m0 + mi * 16 + lg * 4 + r;
        int col = n0 + ni * 16 + ll;
        m2p[base + row * D + col] = acc[mi][ni][r];
      }
  msred[tid] = msa;
  __syncthreads();
  if (tid < 128) msp[(size_t)(k * NCH + cblk) * D + tid] = msred[2 * tid] + msred[2 * tid + 1];
  if (tid < 64) {
    float v = gacc;
#pragma unroll
    for (int off = 1; off < 64; off <<= 1) v += __shfl_xor(v, off);
    if (tid == 0) nkp[k * NCH + cblk] = v;
  }
}

// ---------------------------------------------------------------- pass 4a
__global__ __launch_bounds__(256) void k_redmu(const float* __restrict__ msp,
                                               const float* __restrict__ nkp,
                                               float* __restrict__ Nk,
                                               float* __restrict__ mu) {
  __shared__ float sNk[K];
  int tid = threadIdx.x;
  if (tid < K) {
    float s = 0.f;
    for (int c = 0; c < NCH; ++c) s += nkp[tid * NCH + c];
    sNk[tid] = s;
    Nk[tid] = s;
  }
  __syncthreads();
  for (int it = 0; it < (K * D) / 256; ++it) {
    int idx = it * 256 + tid;
    int k = idx >> 7;
    float s = 0.f;
    for (int c = 0; c < NCH; ++c) s += msp[(size_t)(k * NCH + c) * D + (idx & 127)];
    mu[idx] = s / sNk[k];
  }
}

// ---------------------------------------------------------------- pass 4b
__global__ __launch_bounds__(256) void k_sigma(const float* __restrict__ m2p,
                                               const float* __restrict__ Nk,
                                               const float* __restrict__ mu,
                                               float* __restrict__ sigma) {
  int tid = threadIdx.x;
  int k = blockIdx.y;
  int flat = blockIdx.x * 256 + tid;
  int d = flat >> 7, e = flat & 127;
  float s = 0.f;
  for (int c = 0; c < NCH; ++c) s += m2p[((size_t)(k * NCH + c) << 14) + flat];
  sigma[((size_t)k << 14) + flat] = s / Nk[k] - mu[k * D + d] * mu[k * D + e];
}

// ---------------------------------------------------------------- pass 5
// Blocked symmetric sweep -> Sigma^{-1} (bf16 out), v = Sigma^{-1} mu, c2 = mu.v
#define PBW 36
#define YTW 132
#define AROT(r, c) (((r) << 7) + ((((c) + (((r) >> 3) << 2))) & 127))

__global__ __launch_bounds__(256) void k_inv(const float* __restrict__ sigma,
                                             const float* __restrict__ Nk,
                                             const float* __restrict__ mu,
                                             unsigned short* __restrict__ Bh,
                                             float* __restrict__ vv,
                                             float* __restrict__ coef,
                                             float* __restrict__ c2) {
  __shared__ float A[D * D];
  __shared__ float Pb[32 * PBW];
  __shared__ float Cb[32 * 128];
  __shared__ float Yt[32 * YTW];
  __shared__ float Rb[32 * 128];
  __shared__ float mus[D];
  int tid = threadIdx.x;
  int k = blockIdx.x;
  const float* sg = sigma + ((size_t)k << 14);

#pragma unroll
  for (int i = 0; i < 16; ++i) {
    int f = tid + 256 * i;
    int r = f >> 5, c4 = (f & 31) << 2;
    *(float4*)&A[AROT(r, c4)] = *(const float4*)&sg[((size_t)f) << 2];
  }
  if (tid < D) mus[tid] = mu[k * D + tid];
  __syncthreads();

  float ldet = 0.f;
  int mr = tid >> 3, mq = tid & 7;
  int ci = tid >> 1, ch = tid & 1;
  int w = tid >> 6, l = tid & 63;
  int d0 = (((w >> 1) << 3) + (l >> 3)) * 8;
  int e0 = (((w & 1) << 3) + (l & 7)) * 8;

  for (int t = 0; t < 4; ++t) {
    int tb = t * 32;
    *(float4*)&Pb[mr * PBW + 4 * mq] = *(const float4*)&A[AROT(tb + mr, tb + 4 * mq)];
#pragma unroll
    for (int q = 0; q < 4; ++q) {
      int f = tid + 256 * q;
      int rr = f >> 5, cc4 = (f & 31) << 2;
      *(float4*)&Rb[rr * 128 + cc4] = *(const float4*)&A[AROT(tb + rr, cc4)];
    }
#pragma unroll
    for (int n4 = 0; n4 < 4; ++n4) {
      float4 q4 = *(const float4*)&A[AROT(ci, tb + 16 * ch + 4 * n4)];
      int nb = 16 * ch + 4 * n4;
      Cb[(nb + 0) * 128 + ci] = q4.x;
      Cb[(nb + 1) * 128 + ci] = q4.y;
      Cb[(nb + 2) * 128 + ci] = q4.z;
      Cb[(nb + 3) * 128 + ci] = q4.w;
    }
    __syncthreads();

    for (int c = 0; c < 32; ++c) {
      float dpv = Pb[c * PBW + c];
      float piv = 1.0f / dpv;
      ldet += logf(dpv);
      float4 rq = *(const float4*)&Pb[c * PBW + 4 * mq];
      float cv = Pb[mr * PBW + c];
      __syncthreads();
      float4 rfac = {piv * rq.x, piv * rq.y, piv * rq.z, piv * rq.w};
      float4 own = *(const float4*)&Pb[mr * PBW + 4 * mq];
      bool pr = (mr == c);
      float4 up;
      up.x = pr ? rfac.x : own.x - cv * rfac.x;
      up.y = pr ? rfac.y : own.y - cv * rfac.y;
      up.z = pr ? rfac.z : own.z - cv * rfac.z;
      up.w = pr ? rfac.w : own.w - cv * rfac.w;
      int cq = c >> 2, cl = c & 3;
      if (mq == cq) {
        float nv = pr ? -piv : cv * piv;
        if (cl == 0) up.x = nv;
        else if (cl == 1) up.y = nv;
        else if (cl == 2) up.z = nv;
        else up.w = nv;
      }
      *(float4*)&Pb[mr * PBW + 4 * mq] = up;
      __syncthreads();
    }

    {
      int rs = tid >> 3, cs = tid & 7;
      float accY[4][4] = {};
#pragma unroll 8
      for (int n = 0; n < 32; ++n) {
        float4 cq4 = *(const float4*)&Cb[n * 128 + 4 * rs];
        float4 pq = *(const float4*)&Pb[n * PBW + 4 * cs];
        float ca[4] = {cq4.x, cq4.y, cq4.z, cq4.w};
        float pa[4] = {pq.x, pq.y, pq.z, pq.w};
#pragma unroll
        for (int q = 0; q < 4; ++q)
#pragma unroll
          for (int j = 0; j < 4; ++j) accY[q][j] -= ca[q] * pa[j];
      }
#pragma unroll
      for (int j = 0; j < 4; ++j) {
        float4 o = {accY[0][j], accY[1][j], accY[2][j], accY[3][j]};
        *(float4*)&Yt[(4 * cs + j) * YTW + 4 * rs] = o;
      }
    }
    __syncthreads();

    {
      float acc[8][8];
#pragma unroll
      for (int di = 0; di < 8; ++di)
#pragma unroll
        for (int e4 = 0; e4 < 2; ++e4) {
          float4 a = *(const float4*)&A[AROT(d0 + di, e0 + 4 * e4)];
          acc[di][e4 * 4 + 0] = a.x; acc[di][e4 * 4 + 1] = a.y;
          acc[di][e4 * 4 + 2] = a.z; acc[di][e4 * 4 + 3] = a.w;
        }
#pragma unroll 4
      for (int m = 0; m < 32; ++m) {
        float4 ya = *(const float4*)&Yt[m * YTW + d0];
        float4 yb = *(const float4*)&Yt[m * YTW + d0 + 4];
        float4 ra = *(const float4*)&Rb[m * 128 + e0];
        float4 rb2 = *(const float4*)&Rb[m * 128 + e0 + 4];
        float av[8] = {ya.x, ya.y, ya.z, ya.w, yb.x, yb.y, yb.z, yb.w};
        float bv[8] = {ra.x, ra.y, ra.z, ra.w, rb2.x, rb2.y, rb2.z, rb2.w};
#pragma unroll
        for (int di = 0; di < 8; ++di)
#pragma unroll
          for (int ei = 0; ei < 8; ++ei) acc[di][ei] -= av[di] * bv[ei];
      }
#pragma unroll
      for (int di = 0; di < 8; ++di)
#pragma unroll
        for (int e4 = 0; e4 < 2; ++e4) {
          float4 o = {acc[di][e4 * 4 + 0], acc[di][e4 * 4 + 1],
                      acc[di][e4 * 4 + 2], acc[di][e4 * 4 + 3]};
          *(float4*)&A[AROT(d0 + di, e0 + 4 * e4)] = o;
        }
    }
    __syncthreads();

#pragma unroll
    for (int qq = 0; qq < 4; ++qq) {
      int j0 = 4 * mq + 32 * qq;
      *(float4*)&A[AROT(tb + mr, j0)] = *(const float4*)&Yt[mr * YTW + j0];
    }
    if (ci < tb || ci >= tb + 32) {
#pragma unroll
      for (int n = 0; n < 16; ++n) {
        int mloc = 16 * ch + ((n + ci) & 15);
        A[AROT(ci, tb + mloc)] = Yt[mloc * YTW + ci];
      }
    }
    __syncthreads();
    *(float4*)&A[AROT(tb + mr, tb + 4 * mq)] = *(const float4*)&Pb[mr * PBW + 4 * mq];
    __syncthreads();
  }

  // ---- outputs: Bh = bf16(-A), v = -A mu, c2 = mu.v, coef
#pragma unroll
  for (int i = 0; i < 16; ++i) {
    int f = tid + 256 * i;
    int r = f >> 5, c4 = (f & 31) << 2;
    float4 a = *(const float4*)&A[AROT(r, c4)];
    unsigned u0 = packbf(-a.x, -a.y), u1 = packbf(-a.z, -a.w);
    uint2 o = {u0, u1};
    *(uint2*)(Bh + (size_t)k * (D * D) + f * 4) = o;
  }
  float c2part = 0.f;
  if (tid < D) {
    float s = 0.f;
#pragma unroll 8
    for (int q = 0; q < 32; ++q) {
      float4 a = *(const float4*)&A[AROT(tid, q << 2)];
      float4 m = *(const float4*)&mus[q << 2];
      s += a.x * m.x + a.y * m.y + a.z * m.z + a.w * m.w;
    }
    vv[k * D + tid] = -s;
    c2part = mus[tid] * (-s);
  }
  __syncthreads();
  {
    float v = c2part;
#pragma unroll
    for (int off = 1; off < 64; off <<= 1) v += __shfl_xor(v, off);
    if ((tid & 63) == 0) Pb[tid >> 6] = v;   // reuse Pb as scratch
  }
  __syncthreads();
  if (tid == 0) {
    c2[k] = Pb[0] + Pb[1];
    coef[k] = logf(Nk[k] * (1.0f / (float)S_LEN)) -
              0.5f * ((float)D * LOG_2PI + ldet);
  }
}

// ---------------------------------------------------------------- pass 6
// y = x Sigma^{-1} via MFMA. A-frags + epilogue-x in registers (k-invariant);
// full B_k (32KB) staged per phase, swizzled du^=(e&7); branchless online LSE.
__global__ __launch_bounds__(256) void k_maha(const unsigned short* __restrict__ xb,
                                              const unsigned short* __restrict__ Bh,
                                              const float* __restrict__ vv,
                                              const float* __restrict__ coef,
                                              const float* __restrict__ c2,
                                              float* __restrict__ epart) {
  __shared__ unsigned short Bt[D * D];      // 32KB, row-major in e, unit-swizzled
  __shared__ float vls[K * D];              // 4KB
  __shared__ float cfl[K], c2l[K];
  __shared__ float wsum[4];
  int tid = threadIdx.x;
  int bs = blockIdx.x * MB_S;
  int w = tid >> 6, l = tid & 63;
  int m0 = w * 32;
  int lg = (tid >> 4) & 3, ll = tid & 15;

  // ---- persistent A-fragments: af[mi][jj] = x[bs+m0+mi*16+ll][jj*32+lg*8 ..+8)
  short8 af[2][4];
#pragma unroll
  for (int mi = 0; mi < 2; ++mi) {
    const unsigned short* rp = xb + (size_t)(bs + m0 + mi * 16 + ll) * D;
#pragma unroll
    for (int jj = 0; jj < 4; ++jj)
      af[mi][jj] = *(const short8*)(rp + jj * 32 + lg * 8);
  }
  // ---- persistent epilogue x: ex[mi][r][ni] = x[bs+m0+mi*16+lg*4+r][ll+16*ni]
  unsigned short ex[2][4][8];
#pragma unroll
  for (int mi = 0; mi < 2; ++mi)
#pragma unroll
    for (int r = 0; r < 4; ++r) {
      const unsigned short* rp = xb + (size_t)(bs + m0 + mi * 16 + lg * 4 + r) * D + ll;
#pragma unroll
      for (int ni = 0; ni < 8; ++ni) ex[mi][r][ni] = rp[ni * 16];
    }

  // ---- stage constants
#pragma unroll
  for (int i = 0; i < 4; ++i) { int idx = i * 256 + tid; vls[idx] = vv[idx]; }
  if (tid < K) { cfl[tid] = coef[tid]; c2l[tid] = c2[tid]; }

  // ---- B prefetch k=0 (8 x 16B per thread = full 32KB per block)
  const uint4* bg = (const uint4*)Bh;       // B_k = 2048 16B-units, linear
  uint4 br[8];
#pragma unroll
  for (int j = 0; j < 8; ++j) br[j] = bg[j * 256 + tid];

  float mrun[2][4], srun[2][4];
#pragma unroll
  for (int mi = 0; mi < 2; ++mi)
#pragma unroll
    for (int r = 0; r < 4; ++r) { mrun[mi][r] = -1e30f; srun[mi][r] = 0.f; }

  for (int k = 0; k < K; ++k) {
    // ---- write staged B (swizzled): unit u -> row e=u>>4, du=u&15
#pragma unroll
    for (int j = 0; j < 8; ++j) {
      int u = j * 256 + tid;
      int e = u >> 4, du = u & 15;
      *(uint4*)&Bt[e * D + ((du ^ (e & 7)) << 3)] = br[j];
    }
    // ---- prefetch next k while MFMA phase runs
    if (k + 1 < K) {
      const uint4* src = bg + (size_t)(k + 1) * 2048;
#pragma unroll
      for (int j = 0; j < 8; ++j) br[j] = src[j * 256 + tid];
    }
    __syncthreads();   // Bt ready (first iter: vls/cfl too)

    // ---- MFMA: acc[mi][ni] over full D=128 contraction
    f32x4 acc[2][8];
#pragma unroll
    for (int mi = 0; mi < 2; ++mi)
#pragma unroll
      for (int ni = 0; ni < 8; ++ni) acc[mi][ni] = (f32x4)0.f;
#pragma unroll
    for (int jj = 0; jj < 4; ++jj) {
#pragma unroll
      for (int ni = 0; ni < 8; ++ni) {
        int e = ni * 16 + ll;
        int du = jj * 4 + lg;
        short8 bfr = *(const short8*)&Bt[e * D + ((du ^ (e & 7)) << 3)];
#pragma unroll
        for (int mi = 0; mi < 2; ++mi)
          acc[mi][ni] = __builtin_amdgcn_mfma_f32_16x16x32_bf16(
              af[mi][jj], bfr, acc[mi][ni], 0, 0, 0);
      }
    }

    // ---- epilogue: part = sum_col x*(y - 2v); LSE update (branchless)
    float part[2][4] = {};
#pragma unroll
    for (int ni = 0; ni < 8; ++ni) {
      int col = ni * 16 + ll;
      float w2 = -2.0f * vls[k * D + col];
#pragma unroll
      for (int mi = 0; mi < 2; ++mi)
#pragma unroll
        for (int r = 0; r < 4; ++r)
          part[mi][r] += bfu(ex[mi][r][ni]) * (acc[mi][ni][r] + w2);
    }
#pragma unroll
    for (int mi = 0; mi < 2; ++mi)
#pragma unroll
      for (int r = 0; r < 4; ++r) {
        float p = part[mi][r];
        p += __shfl_xor(p, 1); p += __shfl_xor(p, 2);
        p += __shfl_xor(p, 4); p += __shfl_xor(p, 8);
        float a = cfl[k] - 0.5f * (p + c2l[k]);
        float mn = fmaxf(mrun[mi][r], a);
        srun[mi][r] = srun[mi][r] * expf(mrun[mi][r] - mn) + expf(a - mn);
        mrun[mi][r] = mn;
      }
    __syncthreads();   // MFMA/epilogue done -> Bt free for next k
  }

  // ---- block reduction of log-densities
  float v = 0.f;
#pragma unroll
  for (int mi = 0; mi < 2; ++mi)
#pragma unroll
    for (int r = 0; r < 4; ++r) v += mrun[mi][r] + logf(srun[mi][r]);
  v += __shfl_xor(v, 16);
  v += __shfl_xor(v, 32);
  if (l == 0) wsum[w] = v;
  __syncthreads();
  if (tid == 0) epart[blockIdx.x] = wsum[0] + wsum[1] + wsum[2] + wsum[3];
}

// ---------------------------------------------------------------- pass 7
__global__ __launch_bounds__(256) void k_final(const float* __restrict__ epart,
                                               float* __restrict__ out) {
  __shared__ double sw[4];
  int tid = threadIdx.x;
  double a = (double)epart[tid] + (double)epart[tid + 256];
#pragma unroll
  for (int off = 1; off < 64; off <<= 1) a += __shfl_xor(a, off);
  if ((tid & 63) == 0) sw[tid >> 6] = a;
  __syncthreads();
  if (tid == 0) out[0] = (float)(-(sw[0] + sw[1] + sw[2] + sw[3]));
}

// ----------------------------------------------------------------
extern "C" void kernel_launch(void* const* d_in, const int* in_sizes, int n_in,
                              void* d_out, int out_size, void* d_ws, size_t ws_size,
                              hipStream_t stream) {
  (void)in_sizes; (void)n_in; (void)out_size; (void)ws_size;
  const float* x = (const float*)d_in[0];
  const float* W = (const float*)d_in[1];
  const float* b = (const float*)d_in[2];
  float* out = (float*)d_out;
  float* ws = (float*)d_ws;

  float* gtp   = ws + OFF_GT;
  float* m2p   = ws + OFF_M2P;
  float* msp   = ws + OFF_MSP;
  float* nkp   = ws + OFF_NKP;
  float* Nk    = ws + OFF_NK;
  float* mu    = ws + OFF_MU;
  float* sigma = ws + OFF_SIGMA;
  float* wvp   = ws + OFF_WV;
  float* coefp = ws + OFF_COEF;
  float* c2p   = ws + OFF_C2;
  float* epart = ws + OFF_EPART;
  unsigned short* xb = (unsigned short*)(ws + OFF_XB);
  unsigned short* xt = (unsigned short*)(ws + OFF_XT);
  unsigned short* Bh = (unsigned short*)(ws + OFF_BH);

  k_gamma<<<S_LEN / 256, 256, 0, stream>>>(x, W, b, gtp);
  k_xprep<<<S_LEN / 256, 256, 0, stream>>>(x, xb, xt);
  k_m2<<<dim3(NCH, K), 256, 0, stream>>>(xt, gtp, m2p, msp, nkp);
  k_redmu<<<1, 256, 0, stream>>>(msp, nkp, Nk, mu);
  k_sigma<<<dim3(64, K), 256, 0, stream>>>(m2p, Nk, mu, sigma);
  k_inv<<<K, 256, 0, stream>>>(sigma, Nk, mu, Bh, wvp, coefp, c2p);
  k_maha<<<NMB, 256, 0, stream>>>(xb, Bh, wvp, coefp, c2p, epart);
  k_final<<<1, 256, 0, stream>>>(epart, out);
}